// Round 2
// baseline (7328.793 us; speedup 1.0000x reference)
//
#include <hip/hip_runtime.h>
#include <hip/hip_bf16.h>

typedef __hip_bfloat16 bf16;
typedef short v8s __attribute__((ext_vector_type(8)));
typedef float v4f __attribute__((ext_vector_type(4)));

#define D_ 768
#define S_ 197
#define FF_ 3072
#define MREAL 1576
#define MPAD 1600

__device__ __forceinline__ float b2f(bf16 x){ return __bfloat162float(x); }
__device__ __forceinline__ bf16 f2b(float x){ return __float2bfloat16(x); }
__device__ __forceinline__ unsigned short f2bits(float x){
    union { float f; unsigned u; } t; t.f = x;
    unsigned r = (t.u + 0x7fffu + ((t.u >> 16) & 1u)) >> 16;   // RNE
    return (unsigned short)r;
}
__device__ __forceinline__ v8s pack8(const float4 a, const float4 b){
    union { v8s v; unsigned short u[8]; } r;
    r.u[0]=f2bits(a.x); r.u[1]=f2bits(a.y); r.u[2]=f2bits(a.z); r.u[3]=f2bits(a.w);
    r.u[4]=f2bits(b.x); r.u[5]=f2bits(b.y); r.u[6]=f2bits(b.z); r.u[7]=f2bits(b.w);
    return r.v;
}

// ------------------------- generic MFMA GEMM: C = A @ W^T (+epilogue) -------------------------
// A: [MPAD, K] bf16 row-major (ours). W: [N, K] float32 row-major (model input). C: [MPAD, N].
// ACT: 0 none, 1 relu, 2 quickgelu, 3 *0.1
template<int ACT, bool SSF, int NRES, bool OUTBF>
__global__ __launch_bounds__(256) void gemm_k(
    const bf16* __restrict__ A, const float* __restrict__ W,
    const float* __restrict__ bias, const float* __restrict__ ssf_s, const float* __restrict__ ssf_h,
    const float* res1, const float* res2,
    void* Cout, int N, int K)
{
    const int wid = threadIdx.x >> 6, lane = threadIdx.x & 63;
    const int lr = lane & 15, lq = lane >> 4;
    const int bm = blockIdx.y << 6, bn = blockIdx.x << 6;
    const int wm = (wid >> 1) << 5, wn = (wid & 1) << 5;

    v4f acc[2][2];
    #pragma unroll
    for (int a = 0; a < 2; ++a)
        #pragma unroll
        for (int b = 0; b < 2; ++b)
            acc[a][b] = (v4f){0.f, 0.f, 0.f, 0.f};

    const v8s* A0 = (const v8s*)(A + (size_t)(bm + wm + lr) * K + lq * 8);
    const v8s* A1 = (const v8s*)(A + (size_t)(bm + wm + 16 + lr) * K + lq * 8);
    const float4* B0 = (const float4*)(W + (size_t)(bn + wn + lr) * K + lq * 8);
    const float4* B1 = (const float4*)(W + (size_t)(bn + wn + 16 + lr) * K + lq * 8);
    const int steps = K >> 5;
    for (int t = 0; t < steps; ++t) {
        v8s a0 = A0[t << 2], a1 = A1[t << 2];
        float4 w00 = B0[t << 3], w01 = B0[(t << 3) + 1];
        float4 w10 = B1[t << 3], w11 = B1[(t << 3) + 1];
        v8s b0 = pack8(w00, w01);
        v8s b1 = pack8(w10, w11);
        acc[0][0] = __builtin_amdgcn_mfma_f32_16x16x32_bf16(a0, b0, acc[0][0], 0, 0, 0);
        acc[0][1] = __builtin_amdgcn_mfma_f32_16x16x32_bf16(a0, b1, acc[0][1], 0, 0, 0);
        acc[1][0] = __builtin_amdgcn_mfma_f32_16x16x32_bf16(a1, b0, acc[1][0], 0, 0, 0);
        acc[1][1] = __builtin_amdgcn_mfma_f32_16x16x32_bf16(a1, b1, acc[1][1], 0, 0, 0);
    }

    float bia[2] = {0.f, 0.f}, ss[2] = {1.f, 1.f}, sh[2] = {0.f, 0.f};
    #pragma unroll
    for (int in = 0; in < 2; ++in) {
        int col = bn + wn + in * 16 + lr;
        if (bias) bia[in] = bias[col];
        if (SSF) { ss[in] = ssf_s[col]; sh[in] = ssf_h[col]; }
    }
    #pragma unroll
    for (int im = 0; im < 2; ++im) {
        #pragma unroll
        for (int r = 0; r < 4; ++r) {
            int grow = bm + wm + im * 16 + lq * 4 + r;
            size_t rowoff = (size_t)grow * N;
            #pragma unroll
            for (int in = 0; in < 2; ++in) {
                int gcol = bn + wn + in * 16 + lr;
                float v = acc[im][in][r] + bia[in];
                if (SSF) v = v * ss[in] + sh[in];
                if (ACT == 1) v = fmaxf(v, 0.f);
                if (ACT == 2) v = v / (1.f + __expf(-1.702f * v));
                if (ACT == 3) v = v * 0.1f;
                if (NRES >= 1) v += res1[rowoff + gcol];
                if (NRES >= 2) v += res2[rowoff + gcol];
                if (OUTBF) ((bf16*)Cout)[rowoff + gcol] = f2b(v);
                else       ((float*)Cout)[rowoff + gcol] = v;
            }
        }
    }
}

// ------------------------- LayerNorm: one wave per row -------------------------
template<bool OUTBF>
__global__ __launch_bounds__(256) void ln_k(const float* __restrict__ X, void* Y,
                                            const float* __restrict__ g, const float* __restrict__ b)
{
    int wid = threadIdx.x >> 6, lane = threadIdx.x & 63;
    int row = blockIdx.x * 4 + wid;
    const float* x = X + (size_t)row * D_;
    float v[12], s = 0.f;
    #pragma unroll
    for (int i = 0; i < 12; ++i) { v[i] = x[lane + i * 64]; s += v[i]; }
    #pragma unroll
    for (int o = 32; o; o >>= 1) s += __shfl_xor(s, o, 64);
    float mean = s * (1.f / 768.f);
    float q = 0.f;
    #pragma unroll
    for (int i = 0; i < 12; ++i) { float d = v[i] - mean; q += d * d; }
    #pragma unroll
    for (int o = 32; o; o >>= 1) q += __shfl_xor(q, o, 64);
    float rs = rsqrtf(q * (1.f / 768.f) + 1e-5f);
    #pragma unroll
    for (int i = 0; i < 12; ++i) {
        int d = lane + i * 64;
        float o = (v[i] - mean) * rs * g[d] + b[d];
        if (OUTBF) ((bf16*)Y)[(size_t)row * D_ + d] = f2b(o);
        else       ((float*)Y)[(size_t)row * D_ + d] = o;
    }
}

// final LN on cls rows only -> d_out (float)
__global__ __launch_bounds__(256) void lnpost_k(const float* __restrict__ X, float* out,
                                                const float* __restrict__ g, const float* __restrict__ b)
{
    int wid = threadIdx.x >> 6, lane = threadIdx.x & 63;
    int bi = blockIdx.x * 4 + wid;   // 0..7
    const float* x = X + (size_t)bi * S_ * D_;
    float v[12], s = 0.f;
    #pragma unroll
    for (int i = 0; i < 12; ++i) { v[i] = x[lane + i * 64]; s += v[i]; }
    #pragma unroll
    for (int o = 32; o; o >>= 1) s += __shfl_xor(s, o, 64);
    float mean = s * (1.f / 768.f);
    float q = 0.f;
    #pragma unroll
    for (int i = 0; i < 12; ++i) { float d = v[i] - mean; q += d * d; }
    #pragma unroll
    for (int o = 32; o; o >>= 1) q += __shfl_xor(q, o, 64);
    float rs = rsqrtf(q * (1.f / 768.f) + 1e-5f);
    #pragma unroll
    for (int i = 0; i < 12; ++i) {
        int d = lane + i * 64;
        out[bi * D_ + d] = (v[i] - mean) * rs * g[d] + b[d];
    }
}

// ------------------------- attention: one wave per (b, h, q) -------------------------
__global__ __launch_bounds__(256) void attn_k(const float* __restrict__ qkv, bf16* __restrict__ o)
{
    int wid = threadIdx.x >> 6, lane = threadIdx.x & 63;
    int wg = blockIdx.x * 4 + wid;            // 0..18911
    int q_i = wg % S_; int bh = wg / S_;
    int hh = bh % 12, bb = bh / 12;
    size_t rowq = (size_t)(bb * S_ + q_i) * 2304;
    float qv = qkv[rowq + hh * 64 + lane] * 0.125f;   // 1/sqrt(64)

    size_t kbase = (size_t)(bb * S_) * 2304 + 768 + hh * 64;
    float acc[4] = {0.f, 0.f, 0.f, 0.f};
    for (int c = 0; c < 16; ++c) {
        float q0 = __shfl(qv, c * 4 + 0, 64);
        float q1 = __shfl(qv, c * 4 + 1, 64);
        float q2 = __shfl(qv, c * 4 + 2, 64);
        float q3 = __shfl(qv, c * 4 + 3, 64);
        #pragma unroll
        for (int j = 0; j < 4; ++j) {
            int key = lane + j * 64;
            if (key < S_) {
                const float* kr = qkv + kbase + (size_t)key * 2304 + c * 4;
                float4 kv = *(const float4*)kr;
                acc[j] += kv.x * q0 + kv.y * q1 + kv.z * q2 + kv.w * q3;
            }
        }
    }
    float sc[4], mx = -1e30f;
    #pragma unroll
    for (int j = 0; j < 4; ++j) {
        int key = lane + j * 64;
        sc[j] = (key < S_) ? acc[j] : -1e30f;
        mx = fmaxf(mx, sc[j]);
    }
    #pragma unroll
    for (int off = 32; off; off >>= 1) mx = fmaxf(mx, __shfl_xor(mx, off, 64));
    float p[4], sum = 0.f;
    #pragma unroll
    for (int j = 0; j < 4; ++j) {
        p[j] = (sc[j] > -1e29f) ? __expf(sc[j] - mx) : 0.f;
        sum += p[j];
    }
    #pragma unroll
    for (int off = 32; off; off >>= 1) sum += __shfl_xor(sum, off, 64);
    float inv = 1.f / sum;
    #pragma unroll
    for (int j = 0; j < 4; ++j) p[j] *= inv;

    size_t vbase = (size_t)(bb * S_) * 2304 + 1536 + hh * 64 + lane;
    float accO = 0.f;
    #pragma unroll
    for (int j = 0; j < 4; ++j) {
        int nk = (j < 3) ? 64 : (S_ - 192);
        for (int kk = 0; kk < nk; ++kk) {
            float pk = __shfl(p[j], kk, 64);
            accO += pk * qkv[vbase + (size_t)(j * 64 + kk) * 2304];
        }
    }
    o[(size_t)(bb * S_ + q_i) * D_ + hh * 64 + lane] = f2b(accO);
}

// ------------------------- patch gather: x NCHW (f32) -> [B*196, 768] bf16 (c,kh,kw) ----------
__global__ void patch_k(const float* __restrict__ x, bf16* __restrict__ Pm)
{
    int idx = blockIdx.x * 256 + threadIdx.x;   // < 1568*768 exact
    int col = idx % 768, row = idx / 768;
    int b = row / 196, p = row % 196;
    int py = p / 14, px = p % 14;
    int c = col >> 8, rem = col & 255, kh = rem >> 4, kw = rem & 15;
    Pm[idx] = f2b(x[(((size_t)(b * 3 + c) * 224 + py * 16 + kh) * 224) + px * 16 + kw]);
}

// ------------------------- assemble tokens + pos emb -------------------------
__global__ void assemble_k(const float* __restrict__ E, const float* __restrict__ cls,
                           const float* __restrict__ pos, float* __restrict__ h0)
{
    int idx = blockIdx.x * 256 + threadIdx.x;
    if (idx >= MREAL * D_) return;
    int d = idx % D_, row = idx / D_;
    int b = row / S_, s = row % S_;
    float v = (s == 0) ? cls[d] : E[(size_t)(b * 196 + s - 1) * D_ + d];
    h0[idx] = v + pos[s * D_ + d];
}

// ------------------------- LoRA down: [1576,768]bf16 @ [8,768]f32^T -> [1576,8] -------------------------
__global__ __launch_bounds__(256) void lora_down_k(const bf16* __restrict__ t, const float* __restrict__ Aw,
                                                   float* __restrict__ out)
{
    int wid = threadIdx.x >> 6, lane = threadIdx.x & 63;
    int row = blockIdx.x * 4 + wid;
    const bf16* tr = t + (size_t)row * D_;
    float acc[8] = {0.f,0.f,0.f,0.f,0.f,0.f,0.f,0.f};
    #pragma unroll
    for (int i = 0; i < 12; ++i) {
        int d = lane + i * 64;
        float tv = b2f(tr[d]);
        #pragma unroll
        for (int r = 0; r < 8; ++r) acc[r] += tv * Aw[r * D_ + d];
    }
    #pragma unroll
    for (int r = 0; r < 8; ++r)
        #pragma unroll
        for (int off = 32; off; off >>= 1) acc[r] += __shfl_xor(acc[r], off, 64);
    if (lane == 0) {
        #pragma unroll
        for (int r = 0; r < 8; ++r) out[row * 8 + r] = acc[r];
    }
}

// ------------------------- LoRA up: qkv[:, off:off+768] += s8 @ B^T -------------------------
__global__ void lora_up_k(const float* __restrict__ s8, const float* __restrict__ Bw,
                          float* qkv, int off)
{
    int idx = blockIdx.x * 256 + threadIdx.x;
    if (idx >= MREAL * D_) return;
    int d = idx % D_, row = idx / D_;
    const float* sr = s8 + row * 8;
    const float* br = Bw + d * 8;
    float v = 0.f;
    #pragma unroll
    for (int r = 0; r < 8; ++r) v += sr[r] * br[r];
    qkv[(size_t)row * 2304 + off + d] += v;
}

extern "C" void kernel_launch(void* const* d_in, const int* in_sizes, int n_in,
                              void* d_out, int out_size, void* d_ws, size_t ws_size,
                              hipStream_t stream)
{
    (void)in_sizes; (void)n_in; (void)out_size; (void)ws_size;
    const float* X        = (const float*)d_in[0];
    const float* conv_w   = (const float*)d_in[1];
    const float* cls      = (const float*)d_in[2];
    const float* pos      = (const float*)d_in[3];
    const float* lnpre_g  = (const float*)d_in[4];
    const float* lnpre_b  = (const float*)d_in[5];
    const float* ln1_g    = (const float*)d_in[6];
    const float* ln1_b    = (const float*)d_in[7];
    const float* qkv_w    = (const float*)d_in[8];
    const float* qkv_b    = (const float*)d_in[9];
    const float* ssf_in_s = (const float*)d_in[10];
    const float* ssf_in_h = (const float*)d_in[11];
    const float* lora_q_a = (const float*)d_in[12];
    const float* lora_q_b = (const float*)d_in[13];
    const float* lora_v_a = (const float*)d_in[14];
    const float* lora_v_b = (const float*)d_in[15];
    const float* out_w    = (const float*)d_in[16];
    const float* out_b    = (const float*)d_in[17];
    const float* ssf_o_s  = (const float*)d_in[18];
    const float* ssf_o_h  = (const float*)d_in[19];
    const float* ln2_g    = (const float*)d_in[20];
    const float* ln2_b    = (const float*)d_in[21];
    const float* mi_w     = (const float*)d_in[22];
    const float* mi_b     = (const float*)d_in[23];
    const float* ssf_mi_s = (const float*)d_in[24];
    const float* ssf_mi_h = (const float*)d_in[25];
    const float* mo_w     = (const float*)d_in[26];
    const float* mo_b     = (const float*)d_in[27];
    const float* ssf_mo_s = (const float*)d_in[28];
    const float* ssf_mo_h = (const float*)d_in[29];
    const float* afln_g   = (const float*)d_in[30];
    const float* afln_b   = (const float*)d_in[31];
    const float* afd_w    = (const float*)d_in[32];
    const float* afd_b    = (const float*)d_in[33];
    const float* afu_w    = (const float*)d_in[34];
    const float* afu_b    = (const float*)d_in[35];
    const float* lnpost_g = (const float*)d_in[36];
    const float* lnpost_b = (const float*)d_in[37];

    // workspace layout (bytes)
    char* w = (char*)d_ws;
    float* qkv  = (float*)(w);                         // 1600*2304*4 = 14,745,600
    float* h    = (float*)(w + 14745600);              // 1600*768*4  =  4,915,200
    bf16*  t    = (bf16*)(w + 19660800);               // 1600*768*2  =  2,457,600
    bf16*  mm   = (bf16*)(w + 22118400);               // 1600*3072*2 =  9,830,400
    bf16*  ao   = (bf16*)(w + 31948800);               // 1600*768*2  =  2,457,600
    float* aout = (float*)(w + 34406400);              // 1600*768*4  =  4,915,200
    bf16*  ad   = (bf16*)(w + 39321600);               // 1600*64*2   =    204,800
    float* sq   = (float*)(w + 39526400);              // 1600*8*4    =     51,200
    float* sv   = (float*)(w + 39577600);              // 1600*8*4    =     51,200
    // aliases (pre-layer only):
    bf16*  Pm   = mm;                                  // 1600*768*2 fits in mm
    float* E    = (float*)(w + 22118400 + 2457600);    // 1600*768*4 fits in mm tail
    float* h0   = qkv;

    // patch embed
    patch_k<<<4704, 256, 0, stream>>>(X, Pm);
    gemm_k<0,false,0,false><<<dim3(12,25),256,0,stream>>>(Pm, conv_w, nullptr,nullptr,nullptr,nullptr,nullptr, E, 768, 768);
    assemble_k<<<4729,256,0,stream>>>(E, cls, pos, h0);
    ln_k<false><<<394,256,0,stream>>>(h0, h, lnpre_g, lnpre_b);

    for (int i = 0; i < 12; ++i) {
        // attention
        ln_k<true><<<394,256,0,stream>>>(h, t, ln1_g + i*768, ln1_b + i*768);
        gemm_k<0,true,0,false><<<dim3(36,25),256,0,stream>>>(t, qkv_w + (size_t)i*2304*768,
            qkv_b + i*2304, ssf_in_s + i*2304, ssf_in_h + i*2304, nullptr,nullptr, qkv, 2304, 768);
        lora_down_k<<<394,256,0,stream>>>(t, lora_q_a + (size_t)i*8*768, sq);
        lora_down_k<<<394,256,0,stream>>>(t, lora_v_a + (size_t)i*8*768, sv);
        lora_up_k<<<4729,256,0,stream>>>(sq, lora_q_b + (size_t)i*768*8, qkv, 0);
        lora_up_k<<<4729,256,0,stream>>>(sv, lora_v_b + (size_t)i*768*8, qkv, 1536);
        attn_k<<<4728,256,0,stream>>>(qkv, ao);
        gemm_k<0,true,1,false><<<dim3(12,25),256,0,stream>>>(ao, out_w + (size_t)i*768*768,
            out_b + i*768, ssf_o_s + i*768, ssf_o_h + i*768, h, nullptr, h, 768, 768);
        // AdaptFormer parallel branch (from post-attention h)
        ln_k<true><<<394,256,0,stream>>>(h, t, afln_g + i*768, afln_b + i*768);
        gemm_k<1,false,0,true><<<dim3(1,25),256,0,stream>>>(t, afd_w + (size_t)i*64*768,
            afd_b + i*64, nullptr,nullptr,nullptr,nullptr, ad, 64, 768);
        gemm_k<3,false,0,false><<<dim3(12,25),256,0,stream>>>(ad, afu_w + (size_t)i*768*64,
            afu_b + i*768, nullptr,nullptr,nullptr,nullptr, aout, 768, 64);
        // MLP
        ln_k<true><<<394,256,0,stream>>>(h, t, ln2_g + i*768, ln2_b + i*768);
        gemm_k<2,true,0,true><<<dim3(48,25),256,0,stream>>>(t, mi_w + (size_t)i*3072*768,
            mi_b + i*3072, ssf_mi_s + i*3072, ssf_mi_h + i*3072, nullptr,nullptr, mm, 3072, 768);
        gemm_k<0,true,2,false><<<dim3(12,25),256,0,stream>>>(mm, mo_w + (size_t)i*768*3072,
            mo_b + i*768, ssf_mo_s + i*768, ssf_mo_h + i*768, h, aout, h, 768, 3072);
    }
    lnpost_k<<<2,256,0,stream>>>(h, (float*)d_out, lnpost_g, lnpost_b);
}

// Round 3
// 5234.848 us; speedup vs baseline: 1.4000x; 1.4000x over previous
//
#include <hip/hip_runtime.h>
#include <hip/hip_bf16.h>
#include <stdint.h>

typedef __hip_bfloat16 bf16;
typedef short v8s __attribute__((ext_vector_type(8)));
typedef float v4f __attribute__((ext_vector_type(4)));

#define D_ 768
#define S_ 197
#define MREAL 1576
#define MPAD 1664

__device__ __forceinline__ float b2f(bf16 x){ return __bfloat162float(x); }
__device__ __forceinline__ bf16 f2b(float x){ return __float2bfloat16(x); }
__device__ __forceinline__ unsigned short f2bits(float x){
    union { float f; unsigned u; } t; t.f = x;
    unsigned r = (t.u + 0x7fffu + ((t.u >> 16) & 1u)) >> 16;   // RNE
    return (unsigned short)r;
}
__device__ __forceinline__ v8s pack8(const float4 a, const float4 b){
    union { v8s v; unsigned short u[8]; } r;
    r.u[0]=f2bits(a.x); r.u[1]=f2bits(a.y); r.u[2]=f2bits(a.z); r.u[3]=f2bits(a.w);
    r.u[4]=f2bits(b.x); r.u[5]=f2bits(b.y); r.u[6]=f2bits(b.z); r.u[7]=f2bits(b.w);
    return r.v;
}

// async global->LDS, 16B per lane, wave-uniform LDS base + lane*16
__device__ __forceinline__ void gload16(const void* g, void* l) {
    __builtin_amdgcn_global_load_lds(
        (const __attribute__((address_space(1))) void*)(uintptr_t)g,
        (__attribute__((address_space(3))) void*)(uint32_t)(uintptr_t)l,
        16, 0, 0);
}

// ---------------- 128x128 MFMA GEMM with global_load_lds staging ----------------
// A: [MPAD,K] bf16 row-major. W: [N,K] bf16 row-major. C = A@W^T [MPAD,N].
// ACT: 0 none, 1 relu, 2 quickgelu, 3 *0.1
template<int ACT, bool SSF, int NRES, bool OUTBF>
__global__ __launch_bounds__(256,2) void gemm128_k(
    const bf16* __restrict__ A, const bf16* __restrict__ W,
    const float* __restrict__ bias, const float* __restrict__ ssf_s, const float* __restrict__ ssf_h,
    const float* res1, const float* res2,
    void* Cout, int N, int K)
{
    __shared__ __align__(16) bf16 As[128*32];
    __shared__ __align__(16) bf16 Bs[128*32];
    const int tid = threadIdx.x, wid = tid >> 6, lane = tid & 63;
    const int lr = lane & 15, lq = lane >> 4;
    const int bm = blockIdx.y << 7, bn = blockIdx.x << 7;
    const int wm = ((wid >> 1) & 1) << 6, wn = (wid & 1) << 6;
    const int l4 = lane >> 2, lc = (lane & 3) << 3;   // staging row-in-16 / col-elem

    v4f acc[4][4];
    #pragma unroll
    for (int a = 0; a < 4; ++a)
        #pragma unroll
        for (int b = 0; b < 4; ++b)
            acc[a][b] = (v4f){0.f,0.f,0.f,0.f};

    // each wave stages 32 rows of A-tile and 32 rows of B-tile (2 insts each)
    const bf16* gA0 = A + (size_t)(bm + wid*32 +      l4) * K + lc;
    const bf16* gA1 = A + (size_t)(bm + wid*32 + 16 + l4) * K + lc;
    const bf16* gB0 = W + (size_t)(bn + wid*32 +      l4) * K + lc;
    const bf16* gB1 = W + (size_t)(bn + wid*32 + 16 + l4) * K + lc;
    bf16* lA0 = As + wid*1024;
    bf16* lA1 = As + wid*1024 + 512;
    bf16* lB0 = Bs + wid*1024;
    bf16* lB1 = Bs + wid*1024 + 512;

    for (int k0 = 0; k0 < K; k0 += 32) {
        gload16(gA0 + k0, lA0);
        gload16(gA1 + k0, lA1);
        gload16(gB0 + k0, lB0);
        gload16(gB1 + k0, lB1);
        __syncthreads();
        v8s af[4], bfr[4];
        #pragma unroll
        for (int mi = 0; mi < 4; ++mi) af[mi]  = *(const v8s*)&As[(wm + mi*16 + lr)*32 + lq*8];
        #pragma unroll
        for (int ni = 0; ni < 4; ++ni) bfr[ni] = *(const v8s*)&Bs[(wn + ni*16 + lr)*32 + lq*8];
        #pragma unroll
        for (int mi = 0; mi < 4; ++mi)
            #pragma unroll
            for (int ni = 0; ni < 4; ++ni)
                acc[mi][ni] = __builtin_amdgcn_mfma_f32_16x16x32_bf16(af[mi], bfr[ni], acc[mi][ni], 0, 0, 0);
        __syncthreads();
    }

    float bia[4], ss[4], sh[4];
    #pragma unroll
    for (int ni = 0; ni < 4; ++ni) {
        int col = bn + wn + ni*16 + lr;
        bia[ni] = bias ? bias[col] : 0.f;
        ss[ni] = SSF ? ssf_s[col] : 1.f;
        sh[ni] = SSF ? ssf_h[col] : 0.f;
    }
    #pragma unroll
    for (int mi = 0; mi < 4; ++mi) {
        #pragma unroll
        for (int r = 0; r < 4; ++r) {
            int row = bm + wm + mi*16 + lq*4 + r;
            size_t rowoff = (size_t)row * N;
            #pragma unroll
            for (int ni = 0; ni < 4; ++ni) {
                int col = bn + wn + ni*16 + lr;
                float v = acc[mi][ni][r] + bia[ni];
                if (SSF) v = v * ss[ni] + sh[ni];
                if (ACT == 1) v = fmaxf(v, 0.f);
                if (ACT == 2) v = v / (1.f + __expf(-1.702f * v));
                if (ACT == 3) v = v * 0.1f;
                if (NRES >= 1) v += res1[rowoff + col];
                if (NRES >= 2) v += res2[rowoff + col];
                if (OUTBF) ((bf16*)Cout)[rowoff + col] = f2b(v);
                else       ((float*)Cout)[rowoff + col] = v;
            }
        }
    }
}

// ---------------- AF down: N=64, K=768, direct-load 64-tile GEMM, relu+bias -> bf16 ----------------
__global__ __launch_bounds__(256) void afdown_k(const bf16* __restrict__ A, const bf16* __restrict__ W,
                                                const float* __restrict__ bias, bf16* __restrict__ C)
{
    const int wid = threadIdx.x >> 6, lane = threadIdx.x & 63;
    const int lr = lane & 15, lq = lane >> 4;
    const int bm = blockIdx.x << 6;
    const int wm = (wid >> 1) << 5, wn = (wid & 1) << 5;

    v4f acc[2][2];
    #pragma unroll
    for (int a = 0; a < 2; ++a)
        #pragma unroll
        for (int b = 0; b < 2; ++b) acc[a][b] = (v4f){0.f,0.f,0.f,0.f};

    const v8s* A0 = (const v8s*)(A + (size_t)(bm + wm + lr) * 768 + lq * 8);
    const v8s* A1 = (const v8s*)(A + (size_t)(bm + wm + 16 + lr) * 768 + lq * 8);
    const v8s* B0 = (const v8s*)(W + (size_t)(wn + lr) * 768 + lq * 8);
    const v8s* B1 = (const v8s*)(W + (size_t)(wn + 16 + lr) * 768 + lq * 8);
    for (int t = 0; t < 24; ++t) {
        v8s a0 = A0[t << 2], a1 = A1[t << 2];
        v8s b0 = B0[t << 2], b1 = B1[t << 2];
        acc[0][0] = __builtin_amdgcn_mfma_f32_16x16x32_bf16(a0, b0, acc[0][0], 0, 0, 0);
        acc[0][1] = __builtin_amdgcn_mfma_f32_16x16x32_bf16(a0, b1, acc[0][1], 0, 0, 0);
        acc[1][0] = __builtin_amdgcn_mfma_f32_16x16x32_bf16(a1, b0, acc[1][0], 0, 0, 0);
        acc[1][1] = __builtin_amdgcn_mfma_f32_16x16x32_bf16(a1, b1, acc[1][1], 0, 0, 0);
    }
    #pragma unroll
    for (int im = 0; im < 2; ++im)
        #pragma unroll
        for (int r = 0; r < 4; ++r) {
            int row = bm + wm + im*16 + lq*4 + r;
            #pragma unroll
            for (int in = 0; in < 2; ++in) {
                int col = wn + in*16 + lr;
                float v = fmaxf(acc[im][in][r] + bias[col], 0.f);
                C[(size_t)row * 64 + col] = f2b(v);
            }
        }
}

// ---------------- LayerNorm: one wave per row ----------------
template<bool OUTBF>
__global__ __launch_bounds__(256) void ln_k(const float* __restrict__ X, void* Y,
                                            const float* __restrict__ g, const float* __restrict__ b)
{
    int wid = threadIdx.x >> 6, lane = threadIdx.x & 63;
    int row = blockIdx.x * 4 + wid;
    const float* x = X + (size_t)row * D_;
    float v[12], s = 0.f;
    #pragma unroll
    for (int i = 0; i < 12; ++i) { v[i] = x[lane + i * 64]; s += v[i]; }
    #pragma unroll
    for (int o = 32; o; o >>= 1) s += __shfl_xor(s, o, 64);
    float mean = s * (1.f / 768.f);
    float q = 0.f;
    #pragma unroll
    for (int i = 0; i < 12; ++i) { float d = v[i] - mean; q += d * d; }
    #pragma unroll
    for (int o = 32; o; o >>= 1) q += __shfl_xor(q, o, 64);
    float rs = rsqrtf(q * (1.f / 768.f) + 1e-5f);
    #pragma unroll
    for (int i = 0; i < 12; ++i) {
        int d = lane + i * 64;
        float o = (v[i] - mean) * rs * g[d] + b[d];
        if (OUTBF) ((bf16*)Y)[(size_t)row * D_ + d] = f2b(o);
        else       ((float*)Y)[(size_t)row * D_ + d] = o;
    }
}

__global__ __launch_bounds__(256) void lnpost_k(const float* __restrict__ X, float* out,
                                                const float* __restrict__ g, const float* __restrict__ b)
{
    int wid = threadIdx.x >> 6, lane = threadIdx.x & 63;
    int bi = blockIdx.x * 4 + wid;   // 0..7
    const float* x = X + (size_t)bi * S_ * D_;
    float v[12], s = 0.f;
    #pragma unroll
    for (int i = 0; i < 12; ++i) { v[i] = x[lane + i * 64]; s += v[i]; }
    #pragma unroll
    for (int o = 32; o; o >>= 1) s += __shfl_xor(s, o, 64);
    float mean = s * (1.f / 768.f);
    float q = 0.f;
    #pragma unroll
    for (int i = 0; i < 12; ++i) { float d = v[i] - mean; q += d * d; }
    #pragma unroll
    for (int o = 32; o; o >>= 1) q += __shfl_xor(q, o, 64);
    float rs = rsqrtf(q * (1.f / 768.f) + 1e-5f);
    #pragma unroll
    for (int i = 0; i < 12; ++i) {
        int d = lane + i * 64;
        out[bi * D_ + d] = (v[i] - mean) * rs * g[d] + b[d];
    }
}

// ---------------- attention: block per (qchunk, b*h), K/V staged in LDS (bf16) ----------------
__device__ __forceinline__ void softmax197(float* sc, int lane)
{
    float mx = -1e30f;
    #pragma unroll
    for (int j = 0; j < 4; ++j) {
        if (lane + j*64 >= S_) sc[j] = -1e30f;
        mx = fmaxf(mx, sc[j]);
    }
    #pragma unroll
    for (int off = 32; off; off >>= 1) mx = fmaxf(mx, __shfl_xor(mx, off, 64));
    float sum = 0.f;
    #pragma unroll
    for (int j = 0; j < 4; ++j) {
        sc[j] = (sc[j] > -1e29f) ? __expf(sc[j] - mx) : 0.f;
        sum += sc[j];
    }
    #pragma unroll
    for (int off = 32; off; off >>= 1) sum += __shfl_xor(sum, off, 64);
    float inv = 1.f / sum;
    #pragma unroll
    for (int j = 0; j < 4; ++j) sc[j] *= inv;
}

__global__ __launch_bounds__(256) void attn2_k(const float* __restrict__ qkv, bf16* __restrict__ o)
{
    __shared__ unsigned int   KsU[S_ * 33];   // K as bf16-pairs, stride 33 dwords (bank-spread)
    __shared__ unsigned short VsU[S_ * 64];   // V as bf16 row-major
    const int tid = threadIdx.x, wid = tid >> 6, lane = tid & 63;
    const int qc = blockIdx.x, bh = blockIdx.y;
    const int hh = bh % 12, bb = bh / 12;
    const size_t base = (size_t)(bb * S_) * 2304;

    for (int idx = tid; idx < S_ * 32; idx += 256) {
        int s = idx >> 5, cp = idx & 31;
        const float2 f = *(const float2*)(qkv + base + (size_t)s * 2304 + 768 + hh * 64 + cp * 2);
        KsU[s * 33 + cp] = (unsigned)f2bits(f.x) | ((unsigned)f2bits(f.y) << 16);
    }
    for (int idx = tid; idx < S_ * 64; idx += 256) {
        int s = idx >> 6, d = idx & 63;
        VsU[idx] = f2bits(qkv[base + (size_t)s * 2304 + 1536 + hh * 64 + d]);
    }
    __syncthreads();

    const int qbase = qc * 50;
    const int qend = (qc == 3) ? S_ : (qbase + 50);
    for (int q = qbase + wid * 2; q < qend; q += 8) {
        int qa = q, qb = (q + 1 < qend) ? q + 1 : q;
        float qva = qkv[base + (size_t)qa * 2304 + hh * 64 + lane] * 0.125f;
        float qvb = qkv[base + (size_t)qb * 2304 + hh * 64 + lane] * 0.125f;
        float pA[4] = {0,0,0,0}, pB[4] = {0,0,0,0};
        for (int cp = 0; cp < 32; ++cp) {
            float a0 = __shfl(qva, cp*2, 64),   a1 = __shfl(qva, cp*2 + 1, 64);
            float b0 = __shfl(qvb, cp*2, 64),   b1 = __shfl(qvb, cp*2 + 1, 64);
            #pragma unroll
            for (int j = 0; j < 4; ++j) {
                int key = lane + j * 64;
                if (key < S_) {
                    unsigned kw = KsU[key * 33 + cp];
                    union { unsigned u; float f; } lo, hi;
                    lo.u = kw << 16; hi.u = kw & 0xffff0000u;
                    pA[j] += lo.f * a0 + hi.f * a1;
                    pB[j] += lo.f * b0 + hi.f * b1;
                }
            }
        }
        softmax197(pA, lane);
        softmax197(pB, lane);
        float oA = 0.f, oB = 0.f;
        #pragma unroll
        for (int j = 0; j < 4; ++j) {
            int nk = (j < 3) ? 64 : (S_ - 192);
            for (int kk = 0; kk < nk; ++kk) {
                float pa = __shfl(pA[j], kk, 64);
                float pb = __shfl(pB[j], kk, 64);
                union { unsigned u; float f; } vv;
                vv.u = ((unsigned)VsU[(j * 64 + kk) * 64 + lane]) << 16;
                oA += pa * vv.f;
                oB += pb * vv.f;
            }
        }
        o[(size_t)(bb * S_ + qa) * D_ + hh * 64 + lane] = f2b(oA);
        o[(size_t)(bb * S_ + qb) * D_ + hh * 64 + lane] = f2b(oB);
    }
}

// ---------------- patch gather ----------------
__global__ void patch_k(const float* __restrict__ x, bf16* __restrict__ Pm)
{
    int idx = blockIdx.x * 256 + threadIdx.x;   // 1568*768 exact
    int col = idx % 768, row = idx / 768;
    int b = row / 196, p = row % 196;
    int py = p / 14, px = p % 14;
    int c = col >> 8, rem = col & 255, kh = rem >> 4, kw = rem & 15;
    Pm[idx] = f2b(x[(((size_t)(b * 3 + c) * 224 + py * 16 + kh) * 224) + px * 16 + kw]);
}

__global__ void assemble_k(const float* __restrict__ E, const float* __restrict__ cls,
                           const float* __restrict__ pos, float* __restrict__ h0)
{
    int idx = blockIdx.x * 256 + threadIdx.x;
    if (idx >= MREAL * D_) return;
    int d = idx % D_, row = idx / D_;
    int b = row / S_, s = row % S_;
    float v = (s == 0) ? cls[d] : E[(size_t)(b * 196 + s - 1) * D_ + d];
    h0[idx] = v + pos[s * D_ + d];
}

// ---------------- LoRA (q & v fused via blockIdx.y) ----------------
__global__ __launch_bounds__(256) void lora_down2_k(const bf16* __restrict__ t,
                                                    const float* __restrict__ Aq, const float* __restrict__ Av,
                                                    float* __restrict__ outq, float* __restrict__ outv)
{
    const float* Aw = blockIdx.y ? Av : Aq;
    float* out = blockIdx.y ? outv : outq;
    int wid = threadIdx.x >> 6, lane = threadIdx.x & 63;
    int row = blockIdx.x * 4 + wid;
    const bf16* tr = t + (size_t)row * D_;
    float acc[8] = {0,0,0,0,0,0,0,0};
    #pragma unroll
    for (int i = 0; i < 12; ++i) {
        int d = lane + i * 64;
        float tv = b2f(tr[d]);
        #pragma unroll
        for (int r = 0; r < 8; ++r) acc[r] += tv * Aw[r * D_ + d];
    }
    #pragma unroll
    for (int r = 0; r < 8; ++r)
        #pragma unroll
        for (int off = 32; off; off >>= 1) acc[r] += __shfl_xor(acc[r], off, 64);
    if (lane == 0) {
        #pragma unroll
        for (int r = 0; r < 8; ++r) out[row * 8 + r] = acc[r];
    }
}

__global__ void lora_up2_k(const float* __restrict__ sq, const float* __restrict__ sv,
                           const float* __restrict__ Bq, const float* __restrict__ Bv,
                           float* qkv)
{
    int idx = blockIdx.x * 256 + threadIdx.x;
    if (idx >= MREAL * D_) return;
    const float* s8 = blockIdx.y ? sv : sq;
    const float* Bw = blockIdx.y ? Bv : Bq;
    int off = blockIdx.y ? 1536 : 0;
    int d = idx % D_, row = idx / D_;
    const float* sr = s8 + row * 8;
    const float* br = Bw + d * 8;
    float v = 0.f;
    #pragma unroll
    for (int r = 0; r < 8; ++r) v += sr[r] * br[r];
    qkv[(size_t)row * 2304 + off + d] += v;
}

// ---------------- weight conversion f32 -> bf16 ----------------
__global__ void cvt8_k(const float* __restrict__ src, bf16* __restrict__ dst)
{
    size_t i8 = (size_t)(blockIdx.x * 256 + threadIdx.x) * 8;
    float4 a = *(const float4*)(src + i8);
    float4 b = *(const float4*)(src + i8 + 4);
    *(v8s*)(dst + i8) = pack8(a, b);
}

// layer weights: [qkv 1769472][out 589824][mi 2359296][mo 2359296][afd 49152][afu 49152] = 7176192
__global__ void cvtlayer_k(const float* __restrict__ s0, const float* __restrict__ s1,
                           const float* __restrict__ s2, const float* __restrict__ s3,
                           const float* __restrict__ s4, const float* __restrict__ s5,
                           bf16* __restrict__ dst)
{
    size_t i8 = (size_t)(blockIdx.x * 256 + threadIdx.x) * 8;
    const float* src; size_t loc;
    if      (i8 < 1769472u) { src = s0; loc = i8; }
    else if (i8 < 2359296u) { src = s1; loc = i8 - 1769472u; }
    else if (i8 < 4718592u) { src = s2; loc = i8 - 2359296u; }
    else if (i8 < 7077888u) { src = s3; loc = i8 - 4718592u; }
    else if (i8 < 7127040u) { src = s4; loc = i8 - 7077888u; }
    else                    { src = s5; loc = i8 - 7127040u; }
    float4 a = *(const float4*)(src + loc);
    float4 b = *(const float4*)(src + loc + 4);
    *(v8s*)(dst + i8) = pack8(a, b);
}

extern "C" void kernel_launch(void* const* d_in, const int* in_sizes, int n_in,
                              void* d_out, int out_size, void* d_ws, size_t ws_size,
                              hipStream_t stream)
{
    (void)in_sizes; (void)n_in; (void)out_size; (void)ws_size;
    const float* X        = (const float*)d_in[0];
    const float* conv_w   = (const float*)d_in[1];
    const float* cls      = (const float*)d_in[2];
    const float* pos      = (const float*)d_in[3];
    const float* lnpre_g  = (const float*)d_in[4];
    const float* lnpre_b  = (const float*)d_in[5];
    const float* ln1_g    = (const float*)d_in[6];
    const float* ln1_b    = (const float*)d_in[7];
    const float* qkv_w    = (const float*)d_in[8];
    const float* qkv_b    = (const float*)d_in[9];
    const float* ssf_in_s = (const float*)d_in[10];
    const float* ssf_in_h = (const float*)d_in[11];
    const float* lora_q_a = (const float*)d_in[12];
    const float* lora_q_b = (const float*)d_in[13];
    const float* lora_v_a = (const float*)d_in[14];
    const float* lora_v_b = (const float*)d_in[15];
    const float* out_w    = (const float*)d_in[16];
    const float* out_b    = (const float*)d_in[17];
    const float* ssf_o_s  = (const float*)d_in[18];
    const float* ssf_o_h  = (const float*)d_in[19];
    const float* ln2_g    = (const float*)d_in[20];
    const float* ln2_b    = (const float*)d_in[21];
    const float* mi_w     = (const float*)d_in[22];
    const float* mi_b     = (const float*)d_in[23];
    const float* ssf_mi_s = (const float*)d_in[24];
    const float* ssf_mi_h = (const float*)d_in[25];
    const float* mo_w     = (const float*)d_in[26];
    const float* mo_b     = (const float*)d_in[27];
    const float* ssf_mo_s = (const float*)d_in[28];
    const float* ssf_mo_h = (const float*)d_in[29];
    const float* afln_g   = (const float*)d_in[30];
    const float* afln_b   = (const float*)d_in[31];
    const float* afd_w    = (const float*)d_in[32];
    const float* afd_b    = (const float*)d_in[33];
    const float* afu_w    = (const float*)d_in[34];
    const float* afu_b    = (const float*)d_in[35];
    const float* lnpost_g = (const float*)d_in[36];
    const float* lnpost_b = (const float*)d_in[37];

    // workspace layout (MPAD = 1664 rows)
    char* w = (char*)d_ws;
    float* qkv  = (float*)(w);                   // 15,335,424
    float* h    = (float*)(w + 15335424);        //  5,111,808
    bf16*  t    = (bf16*)(w + 20447232);         //  2,555,904
    bf16*  mm   = (bf16*)(w + 23003136);         // 10,223,616
    bf16*  ao   = (bf16*)(w + 33226752);         //  2,555,904
    bf16*  ad   = (bf16*)(w + 35782656);         //    212,992
    float* sq   = (float*)(w + 35995648);        //     53,248
    float* sv   = (float*)(w + 36048896);        //     53,248
    bf16*  wbuf = (bf16*)(w + 36102144);         // 14,352,384 (end 50,454,528)
    // aliases:
    float* aout  = qkv;                          // AF-up output; qkv dead after attn
    bf16*  Pm    = mm;                           // pre-loop only
    float* E     = (float*)(w + 25559040);       // pre-loop only (inside mm)
    float* h0    = qkv;                          // pre-loop only
    bf16*  wconv = wbuf;                         // pre-loop only

    // weight sub-offsets in wbuf (elements)
    const size_t WQ = 0, WO = 1769472, WMI = 2359296, WMO = 4718592, WAD = 7077888, WAU = 7127040;

    // ---- patch embed ----
    cvt8_k<<<288, 256, 0, stream>>>(conv_w, wconv);
    patch_k<<<4704, 256, 0, stream>>>(X, Pm);
    gemm128_k<0,false,0,false><<<dim3(6,13), 256, 0, stream>>>(Pm, wconv,
        nullptr, nullptr, nullptr, nullptr, nullptr, E, 768, 768);
    assemble_k<<<4729, 256, 0, stream>>>(E, cls, pos, h0);
    ln_k<false><<<394, 256, 0, stream>>>(h0, h, lnpre_g, lnpre_b);

    for (int i = 0; i < 12; ++i) {
        cvtlayer_k<<<3504, 256, 0, stream>>>(
            qkv_w + (size_t)i * 1769472u, out_w + (size_t)i * 589824u,
            mi_w  + (size_t)i * 2359296u, mo_w  + (size_t)i * 2359296u,
            afd_w + (size_t)i * 49152u,   afu_w + (size_t)i * 49152u, wbuf);
        // attention
        ln_k<true><<<394, 256, 0, stream>>>(h, t, ln1_g + i*768, ln1_b + i*768);
        gemm128_k<0,true,0,false><<<dim3(18,13), 256, 0, stream>>>(t, wbuf + WQ,
            qkv_b + i*2304, ssf_in_s + i*2304, ssf_in_h + i*2304, nullptr, nullptr, qkv, 2304, 768);
        lora_down2_k<<<dim3(394,2), 256, 0, stream>>>(t,
            lora_q_a + (size_t)i*6144, lora_v_a + (size_t)i*6144, sq, sv);
        lora_up2_k<<<dim3(4729,2), 256, 0, stream>>>(sq, sv,
            lora_q_b + (size_t)i*6144, lora_v_b + (size_t)i*6144, qkv);
        attn2_k<<<dim3(4,96), 256, 0, stream>>>(qkv, ao);
        gemm128_k<0,true,1,false><<<dim3(6,13), 256, 0, stream>>>(ao, wbuf + WO,
            out_b + i*768, ssf_o_s + i*768, ssf_o_h + i*768, h, nullptr, h, 768, 768);
        // AdaptFormer parallel branch
        ln_k<true><<<394, 256, 0, stream>>>(h, t, afln_g + i*768, afln_b + i*768);
        afdown_k<<<26, 256, 0, stream>>>(t, wbuf + WAD, afd_b + i*64, ad);
        gemm128_k<3,false,0,false><<<dim3(6,13), 256, 0, stream>>>(ad, wbuf + WAU,
            afu_b + i*768, nullptr, nullptr, nullptr, nullptr, aout, 768, 64);
        // MLP
        ln_k<true><<<394, 256, 0, stream>>>(h, t, ln2_g + i*768, ln2_b + i*768);
        gemm128_k<2,true,0,true><<<dim3(24,13), 256, 0, stream>>>(t, wbuf + WMI,
            mi_b + i*3072, ssf_mi_s + i*3072, ssf_mi_h + i*3072, nullptr, nullptr, mm, 3072, 768);
        gemm128_k<0,true,2,false><<<dim3(6,13), 256, 0, stream>>>(mm, wbuf + WMO,
            mo_b + i*768, ssf_mo_s + i*768, ssf_mo_h + i*768, h, aout, h, 768, 3072);
    }
    lnpost_k<<<2, 256, 0, stream>>>(h, (float*)d_out, lnpost_g, lnpost_b);
}

// Round 4
// 3121.011 us; speedup vs baseline: 2.3482x; 1.6773x over previous
//
#include <hip/hip_runtime.h>
#include <hip/hip_bf16.h>
#include <stdint.h>

typedef __hip_bfloat16 bf16;
typedef short v8s __attribute__((ext_vector_type(8)));
typedef float v4f __attribute__((ext_vector_type(4)));

#define D_ 768
#define S_ 197
#define MREAL 1576
#define MPAD 1664

__device__ __forceinline__ float b2f(bf16 x){ return __bfloat162float(x); }
__device__ __forceinline__ bf16 f2b(float x){ return __float2bfloat16(x); }
__device__ __forceinline__ unsigned short f2bits(float x){
    union { float f; unsigned u; } t; t.f = x;
    unsigned r = (t.u + 0x7fffu + ((t.u >> 16) & 1u)) >> 16;   // RNE
    return (unsigned short)r;
}
__device__ __forceinline__ v8s pack8(const float4 a, const float4 b){
    union { v8s v; unsigned short u[8]; } r;
    r.u[0]=f2bits(a.x); r.u[1]=f2bits(a.y); r.u[2]=f2bits(a.z); r.u[3]=f2bits(a.w);
    r.u[4]=f2bits(b.x); r.u[5]=f2bits(b.y); r.u[6]=f2bits(b.z); r.u[7]=f2bits(b.w);
    return r.v;
}

// async global->LDS, 16B per lane, wave-uniform LDS base + lane*16
__device__ __forceinline__ void gload16(const void* g, void* l) {
    __builtin_amdgcn_global_load_lds(
        (const __attribute__((address_space(1))) void*)(uintptr_t)g,
        (__attribute__((address_space(3))) void*)(uint32_t)(uintptr_t)l,
        16, 0, 0);
}

// ---------------- 128x128 MFMA GEMM with global_load_lds staging ----------------
// A: [MPAD,K] bf16 row-major. W: [N,K] bf16 row-major. C = A@W^T [MPAD,N].
// ACT: 0 none, 1 relu, 2 quickgelu, 3 *0.1
template<int ACT, bool SSF, int NRES, bool OUTBF>
__global__ __launch_bounds__(256,2) void gemm128_k(
    const bf16* __restrict__ A, const bf16* __restrict__ W,
    const float* __restrict__ bias, const float* __restrict__ ssf_s, const float* __restrict__ ssf_h,
    const float* res1, const float* res2,
    void* Cout, int N, int K)
{
    __shared__ __align__(16) bf16 As[128*32];
    __shared__ __align__(16) bf16 Bs[128*32];
    const int tid = threadIdx.x, wid = tid >> 6, lane = tid & 63;
    const int lr = lane & 15, lq = lane >> 4;
    const int bm = blockIdx.y << 7, bn = blockIdx.x << 7;
    const int wm = ((wid >> 1) & 1) << 6, wn = (wid & 1) << 6;
    const int l4 = lane >> 2, lc = (lane & 3) << 3;   // staging row-in-16 / col-elem

    v4f acc[4][4];
    #pragma unroll
    for (int a = 0; a < 4; ++a)
        #pragma unroll
        for (int b = 0; b < 4; ++b)
            acc[a][b] = (v4f){0.f,0.f,0.f,0.f};

    const bf16* gA0 = A + (size_t)(bm + wid*32 +      l4) * K + lc;
    const bf16* gA1 = A + (size_t)(bm + wid*32 + 16 + l4) * K + lc;
    const bf16* gB0 = W + (size_t)(bn + wid*32 +      l4) * K + lc;
    const bf16* gB1 = W + (size_t)(bn + wid*32 + 16 + l4) * K + lc;
    bf16* lA0 = As + wid*1024;
    bf16* lA1 = As + wid*1024 + 512;
    bf16* lB0 = Bs + wid*1024;
    bf16* lB1 = Bs + wid*1024 + 512;

    for (int k0 = 0; k0 < K; k0 += 32) {
        gload16(gA0 + k0, lA0);
        gload16(gA1 + k0, lA1);
        gload16(gB0 + k0, lB0);
        gload16(gB1 + k0, lB1);
        __syncthreads();
        v8s af[4], bfr[4];
        #pragma unroll
        for (int mi = 0; mi < 4; ++mi) af[mi]  = *(const v8s*)&As[(wm + mi*16 + lr)*32 + lq*8];
        #pragma unroll
        for (int ni = 0; ni < 4; ++ni) bfr[ni] = *(const v8s*)&Bs[(wn + ni*16 + lr)*32 + lq*8];
        #pragma unroll
        for (int mi = 0; mi < 4; ++mi)
            #pragma unroll
            for (int ni = 0; ni < 4; ++ni)
                acc[mi][ni] = __builtin_amdgcn_mfma_f32_16x16x32_bf16(af[mi], bfr[ni], acc[mi][ni], 0, 0, 0);
        __syncthreads();
    }

    float bia[4], ss[4], sh[4];
    #pragma unroll
    for (int ni = 0; ni < 4; ++ni) {
        int col = bn + wn + ni*16 + lr;
        bia[ni] = bias ? bias[col] : 0.f;
        ss[ni] = SSF ? ssf_s[col] : 1.f;
        sh[ni] = SSF ? ssf_h[col] : 0.f;
    }
    #pragma unroll
    for (int mi = 0; mi < 4; ++mi) {
        #pragma unroll
        for (int r = 0; r < 4; ++r) {
            int row = bm + wm + mi*16 + lq*4 + r;
            size_t rowoff = (size_t)row * N;
            #pragma unroll
            for (int ni = 0; ni < 4; ++ni) {
                int col = bn + wn + ni*16 + lr;
                float v = acc[mi][ni][r] + bia[ni];
                if (SSF) v = v * ss[ni] + sh[ni];
                if (ACT == 1) v = fmaxf(v, 0.f);
                if (ACT == 2) v = v / (1.f + __expf(-1.702f * v));
                if (ACT == 3) v = v * 0.1f;
                if (NRES >= 1) v += res1[rowoff + col];
                if (NRES >= 2) v += res2[rowoff + col];
                if (OUTBF) ((bf16*)Cout)[rowoff + col] = f2b(v);
                else       ((float*)Cout)[rowoff + col] = v;
            }
        }
    }
}

// ---------------- AF down: N=64, K=768, direct-load 64-tile GEMM, relu+bias -> bf16 ----------------
__global__ __launch_bounds__(256) void afdown_k(const bf16* __restrict__ A, const bf16* __restrict__ W,
                                                const float* __restrict__ bias, bf16* __restrict__ C)
{
    const int wid = threadIdx.x >> 6, lane = threadIdx.x & 63;
    const int lr = lane & 15, lq = lane >> 4;
    const int bm = blockIdx.x << 6;
    const int wm = (wid >> 1) << 5, wn = (wid & 1) << 5;

    v4f acc[2][2];
    #pragma unroll
    for (int a = 0; a < 2; ++a)
        #pragma unroll
        for (int b = 0; b < 2; ++b) acc[a][b] = (v4f){0.f,0.f,0.f,0.f};

    const v8s* A0 = (const v8s*)(A + (size_t)(bm + wm + lr) * 768 + lq * 8);
    const v8s* A1 = (const v8s*)(A + (size_t)(bm + wm + 16 + lr) * 768 + lq * 8);
    const v8s* B0 = (const v8s*)(W + (size_t)(wn + lr) * 768 + lq * 8);
    const v8s* B1 = (const v8s*)(W + (size_t)(wn + 16 + lr) * 768 + lq * 8);
    for (int t = 0; t < 24; ++t) {
        v8s a0 = A0[t << 2], a1 = A1[t << 2];
        v8s b0 = B0[t << 2], b1 = B1[t << 2];
        acc[0][0] = __builtin_amdgcn_mfma_f32_16x16x32_bf16(a0, b0, acc[0][0], 0, 0, 0);
        acc[0][1] = __builtin_amdgcn_mfma_f32_16x16x32_bf16(a0, b1, acc[0][1], 0, 0, 0);
        acc[1][0] = __builtin_amdgcn_mfma_f32_16x16x32_bf16(a1, b0, acc[1][0], 0, 0, 0);
        acc[1][1] = __builtin_amdgcn_mfma_f32_16x16x32_bf16(a1, b1, acc[1][1], 0, 0, 0);
    }
    #pragma unroll
    for (int im = 0; im < 2; ++im)
        #pragma unroll
        for (int r = 0; r < 4; ++r) {
            int row = bm + wm + im*16 + lq*4 + r;
            #pragma unroll
            for (int in = 0; in < 2; ++in) {
                int col = wn + in*16 + lr;
                float v = fmaxf(acc[im][in][r] + bias[col], 0.f);
                C[(size_t)row * 64 + col] = f2b(v);
            }
        }
}

// ---------------- LayerNorm: one wave per row ----------------
template<bool OUTBF>
__global__ __launch_bounds__(256) void ln_k(const float* __restrict__ X, void* Y,
                                            const float* __restrict__ g, const float* __restrict__ b)
{
    int wid = threadIdx.x >> 6, lane = threadIdx.x & 63;
    int row = blockIdx.x * 4 + wid;
    const float* x = X + (size_t)row * D_;
    float v[12], s = 0.f;
    #pragma unroll
    for (int i = 0; i < 12; ++i) { v[i] = x[lane + i * 64]; s += v[i]; }
    #pragma unroll
    for (int o = 32; o; o >>= 1) s += __shfl_xor(s, o, 64);
    float mean = s * (1.f / 768.f);
    float q = 0.f;
    #pragma unroll
    for (int i = 0; i < 12; ++i) { float d = v[i] - mean; q += d * d; }
    #pragma unroll
    for (int o = 32; o; o >>= 1) q += __shfl_xor(q, o, 64);
    float rs = rsqrtf(q * (1.f / 768.f) + 1e-5f);
    #pragma unroll
    for (int i = 0; i < 12; ++i) {
        int d = lane + i * 64;
        float o = (v[i] - mean) * rs * g[d] + b[d];
        if (OUTBF) ((bf16*)Y)[(size_t)row * D_ + d] = f2b(o);
        else       ((float*)Y)[(size_t)row * D_ + d] = o;
    }
}

__global__ __launch_bounds__(256) void lnpost_k(const float* __restrict__ X, float* out,
                                                const float* __restrict__ g, const float* __restrict__ b)
{
    int wid = threadIdx.x >> 6, lane = threadIdx.x & 63;
    int bi = blockIdx.x * 4 + wid;   // 0..7
    const float* x = X + (size_t)bi * S_ * D_;
    float v[12], s = 0.f;
    #pragma unroll
    for (int i = 0; i < 12; ++i) { v[i] = x[lane + i * 64]; s += v[i]; }
    #pragma unroll
    for (int o = 32; o; o >>= 1) s += __shfl_xor(s, o, 64);
    float mean = s * (1.f / 768.f);
    float q = 0.f;
    #pragma unroll
    for (int i = 0; i < 12; ++i) { float d = v[i] - mean; q += d * d; }
    #pragma unroll
    for (int o = 32; o; o >>= 1) q += __shfl_xor(q, o, 64);
    float rs = rsqrtf(q * (1.f / 768.f) + 1e-5f);
    #pragma unroll
    for (int i = 0; i < 12; ++i) {
        int d = lane + i * 64;
        out[bi * D_ + d] = (v[i] - mean) * rs * g[d] + b[d];
    }
}

// ---------------- MFMA flash attention ----------------
// grid (4, 96): blockIdx.x = q-block (64 rows), blockIdx.y = b*12+h.
// K,V staged in LDS pre-arranged in MFMA fragment order. One 16-row Q-tile/wave.
__global__ __launch_bounds__(256) void attn3_k(const float* __restrict__ qkv, bf16* __restrict__ o)
{
    // region A: K fragments (13312 u16) then reused for P fragments (4 waves x 3584 u16)
    __shared__ __align__(16) unsigned short smA[14336];
    __shared__ __align__(16) unsigned short smV[14336];
    const int tid = threadIdx.x, wid = tid >> 6, lane = tid & 63;
    const int quad = lane >> 4, l15 = lane & 15;
    const int qblk = blockIdx.x, bh = blockIdx.y;
    const int hh = bh % 12, bb = bh / 12;
    const size_t base = (size_t)(bb * S_) * 2304;

    // ---- stage K in B-fragment order: frag(kt,step): lane l = ((d&31)>>3)<<4 | (key&15), j = d&7
    for (int idx = tid; idx < 197 * 32; idx += 256) {
        int key = idx >> 5, d = (idx & 31) << 1;
        float2 f = *(const float2*)(qkv + base + (size_t)key * 2304 + 768 + hh * 64 + d);
        unsigned pr = (unsigned)f2bits(f.x) | ((unsigned)f2bits(f.y) << 16);
        int elem = ((key >> 4) << 10) + ((d >> 5) << 9) + (((d & 31) >> 3) << 7) + ((key & 15) << 3) + (d & 7);
        *(unsigned*)(smA + elem) = pr;
    }
    // ---- stage V in B-fragment order (keys padded 197..223 = 0): lane l = ((key>>3)&3)<<4 | (d&15), j = key&7
    for (int idx = tid; idx < 224 * 64; idx += 256) {
        int key = idx >> 6, d = idx & 63;
        unsigned short hv = 0;
        if (key < 197) hv = f2bits(qkv[base + (size_t)key * 2304 + 1536 + hh * 64 + d]);
        int elem = (((key >> 5) << 2) + (d >> 4)) * 512 + (((key >> 3) & 3) * 16 + (d & 15)) * 8 + (key & 7);
        smV[elem] = hv;
    }
    __syncthreads();

    const int q0 = qblk * 64 + wid * 16;
    const bool active = (q0 < 208);
    v4f sc[13];
    float inv[4];
    if (active) {
        // Q fragments (f32 -> bf16 pack), row clamped for the partial tile
        int qrow = q0 + l15; if (qrow > 196) qrow = 196;
        const float* qp = qkv + base + (size_t)qrow * 2304 + hh * 64 + quad * 8;
        v8s qf0 = pack8(*(const float4*)qp,        *(const float4*)(qp + 4));
        v8s qf1 = pack8(*(const float4*)(qp + 32), *(const float4*)(qp + 36));
        #pragma unroll
        for (int kt = 0; kt < 13; ++kt) {
            sc[kt] = (v4f){0.f,0.f,0.f,0.f};
            sc[kt] = __builtin_amdgcn_mfma_f32_16x16x32_bf16(qf0, *(const v8s*)&smA[kt*1024 + lane*8],       sc[kt], 0,0,0);
            sc[kt] = __builtin_amdgcn_mfma_f32_16x16x32_bf16(qf1, *(const v8s*)&smA[kt*1024 + 512 + lane*8], sc[kt], 0,0,0);
        }
        // scale + mask + row softmax (row = quad*4 + r; reduce across 16 lanes sharing quad)
        float mx[4] = {-1e30f,-1e30f,-1e30f,-1e30f};
        #pragma unroll
        for (int kt = 0; kt < 13; ++kt)
            #pragma unroll
            for (int r = 0; r < 4; ++r) {
                float v = sc[kt][r] * 0.125f;
                if (kt == 12 && l15 >= 5) v = -1e30f;
                sc[kt][r] = v;
                mx[r] = fmaxf(mx[r], v);
            }
        #pragma unroll
        for (int r = 0; r < 4; ++r)
            #pragma unroll
            for (int off = 1; off < 16; off <<= 1) mx[r] = fmaxf(mx[r], __shfl_xor(mx[r], off, 64));
        float sum[4] = {0.f,0.f,0.f,0.f};
        #pragma unroll
        for (int kt = 0; kt < 13; ++kt)
            #pragma unroll
            for (int r = 0; r < 4; ++r) {
                float p = (kt == 12 && l15 >= 5) ? 0.f : __expf(sc[kt][r] - mx[r]);
                sc[kt][r] = p;
                sum[r] += p;
            }
        #pragma unroll
        for (int r = 0; r < 4; ++r) {
            #pragma unroll
            for (int off = 1; off < 16; off <<= 1) sum[r] += __shfl_xor(sum[r], off, 64);
            inv[r] = 1.f / sum[r];
        }
    }
    __syncthreads();   // all QK reads of smA done; reuse region A for P fragments
    if (active) {
        unsigned short* pf = smA + wid * 3584;
        // zero P for pad keys 208..223 (kt2=6 upper half)
        *(unsigned long long*)(pf + 6*512 + 256 + lane*4) = 0ULL;
        // write P in A-fragment order: l = ((key>>3)&3)<<4 | row, j = key&7
        #pragma unroll
        for (int kt = 0; kt < 13; ++kt) {
            int key = kt * 16 + l15;
            int ebase = ((key >> 5) << 9) + (((key >> 3) & 3) << 7) + (key & 7);
            #pragma unroll
            for (int r = 0; r < 4; ++r) {
                int row = quad * 4 + r;
                pf[ebase + row * 8] = f2bits(sc[kt][r]);
            }
        }
        v4f oa[4];
        #pragma unroll
        for (int nt = 0; nt < 4; ++nt) oa[nt] = (v4f){0.f,0.f,0.f,0.f};
        #pragma unroll
        for (int kt2 = 0; kt2 < 7; ++kt2) {
            v8s pfr = *(const v8s*)(pf + kt2 * 512 + lane * 8);
            #pragma unroll
            for (int nt = 0; nt < 4; ++nt) {
                v8s vf = *(const v8s*)(smV + (kt2 * 4 + nt) * 512 + lane * 8);
                oa[nt] = __builtin_amdgcn_mfma_f32_16x16x32_bf16(pfr, vf, oa[nt], 0, 0, 0);
            }
        }
        #pragma unroll
        for (int r = 0; r < 4; ++r) {
            int q = q0 + quad * 4 + r;
            if (q < 197) {
                bf16* op = o + (size_t)(bb * S_ + q) * 768 + hh * 64 + l15;
                #pragma unroll
                for (int nt = 0; nt < 4; ++nt) op[nt * 16] = f2b(oa[nt][r] * inv[r]);
            }
        }
    }
}

// ---------------- patch gather ----------------
__global__ void patch_k(const float* __restrict__ x, bf16* __restrict__ Pm)
{
    int idx = blockIdx.x * 256 + threadIdx.x;   // 1568*768 exact
    int col = idx % 768, row = idx / 768;
    int b = row / 196, p = row % 196;
    int py = p / 14, px = p % 14;
    int c = col >> 8, rem = col & 255, kh = rem >> 4, kw = rem & 15;
    Pm[idx] = f2b(x[(((size_t)(b * 3 + c) * 224 + py * 16 + kh) * 224) + px * 16 + kw]);
}

__global__ void assemble_k(const float* __restrict__ E, const float* __restrict__ cls,
                           const float* __restrict__ pos, float* __restrict__ h0)
{
    int idx = blockIdx.x * 256 + threadIdx.x;
    if (idx >= MREAL * D_) return;
    int d = idx % D_, row = idx / D_;
    int b = row / S_, s = row % S_;
    float v = (s == 0) ? cls[d] : E[(size_t)(b * 196 + s - 1) * D_ + d];
    h0[idx] = v + pos[s * D_ + d];
}

// ---------------- LoRA (q & v fused via blockIdx.y) ----------------
__global__ __launch_bounds__(256) void lora_down2_k(const bf16* __restrict__ t,
                                                    const float* __restrict__ Aq, const float* __restrict__ Av,
                                                    float* __restrict__ outq, float* __restrict__ outv)
{
    const float* Aw = blockIdx.y ? Av : Aq;
    float* out = blockIdx.y ? outv : outq;
    int wid = threadIdx.x >> 6, lane = threadIdx.x & 63;
    int row = blockIdx.x * 4 + wid;
    const bf16* tr = t + (size_t)row * D_;
    float acc[8] = {0,0,0,0,0,0,0,0};
    #pragma unroll
    for (int i = 0; i < 12; ++i) {
        int d = lane + i * 64;
        float tv = b2f(tr[d]);
        #pragma unroll
        for (int r = 0; r < 8; ++r) acc[r] += tv * Aw[r * D_ + d];
    }
    #pragma unroll
    for (int r = 0; r < 8; ++r)
        #pragma unroll
        for (int off = 32; off; off >>= 1) acc[r] += __shfl_xor(acc[r], off, 64);
    if (lane == 0) {
        #pragma unroll
        for (int r = 0; r < 8; ++r) out[row * 8 + r] = acc[r];
    }
}

__global__ void lora_up2_k(const float* __restrict__ sq, const float* __restrict__ sv,
                           const float* __restrict__ Bq, const float* __restrict__ Bv,
                           float* qkv)
{
    int idx = blockIdx.x * 256 + threadIdx.x;
    if (idx >= MREAL * D_) return;
    const float* s8 = blockIdx.y ? sv : sq;
    const float* Bw = blockIdx.y ? Bv : Bq;
    int off = blockIdx.y ? 1536 : 0;
    int d = idx % D_, row = idx / D_;
    const float* sr = s8 + row * 8;
    const float* br = Bw + d * 8;
    float v = 0.f;
    #pragma unroll
    for (int r = 0; r < 8; ++r) v += sr[r] * br[r];
    qkv[(size_t)row * 2304 + off + d] += v;
}

// ---------------- weight conversion f32 -> bf16 ----------------
__global__ void cvt8_k(const float* __restrict__ src, bf16* __restrict__ dst)
{
    size_t i8 = (size_t)(blockIdx.x * 256 + threadIdx.x) * 8;
    float4 a = *(const float4*)(src + i8);
    float4 b = *(const float4*)(src + i8 + 4);
    *(v8s*)(dst + i8) = pack8(a, b);
}

// layer weights: [qkv 1769472][out 589824][mi 2359296][mo 2359296][afd 49152][afu 49152] = 7176192
__global__ void cvtlayer_k(const float* __restrict__ s0, const float* __restrict__ s1,
                           const float* __restrict__ s2, const float* __restrict__ s3,
                           const float* __restrict__ s4, const float* __restrict__ s5,
                           bf16* __restrict__ dst)
{
    size_t i8 = (size_t)(blockIdx.x * 256 + threadIdx.x) * 8;
    const float* src; size_t loc;
    if      (i8 < 1769472u) { src = s0; loc = i8; }
    else if (i8 < 2359296u) { src = s1; loc = i8 - 1769472u; }
    else if (i8 < 4718592u) { src = s2; loc = i8 - 2359296u; }
    else if (i8 < 7077888u) { src = s3; loc = i8 - 4718592u; }
    else if (i8 < 7127040u) { src = s4; loc = i8 - 7077888u; }
    else                    { src = s5; loc = i8 - 7127040u; }
    float4 a = *(const float4*)(src + loc);
    float4 b = *(const float4*)(src + loc + 4);
    *(v8s*)(dst + i8) = pack8(a, b);
}

extern "C" void kernel_launch(void* const* d_in, const int* in_sizes, int n_in,
                              void* d_out, int out_size, void* d_ws, size_t ws_size,
                              hipStream_t stream)
{
    (void)in_sizes; (void)n_in; (void)out_size; (void)ws_size;
    const float* X        = (const float*)d_in[0];
    const float* conv_w   = (const float*)d_in[1];
    const float* cls      = (const float*)d_in[2];
    const float* pos      = (const float*)d_in[3];
    const float* lnpre_g  = (const float*)d_in[4];
    const float* lnpre_b  = (const float*)d_in[5];
    const float* ln1_g    = (const float*)d_in[6];
    const float* ln1_b    = (const float*)d_in[7];
    const float* qkv_w    = (const float*)d_in[8];
    const float* qkv_b    = (const float*)d_in[9];
    const float* ssf_in_s = (const float*)d_in[10];
    const float* ssf_in_h = (const float*)d_in[11];
    const float* lora_q_a = (const float*)d_in[12];
    const float* lora_q_b = (const float*)d_in[13];
    const float* lora_v_a = (const float*)d_in[14];
    const float* lora_v_b = (const float*)d_in[15];
    const float* out_w    = (const float*)d_in[16];
    const float* out_b    = (const float*)d_in[17];
    const float* ssf_o_s  = (const float*)d_in[18];
    const float* ssf_o_h  = (const float*)d_in[19];
    const float* ln2_g    = (const float*)d_in[20];
    const float* ln2_b    = (const float*)d_in[21];
    const float* mi_w     = (const float*)d_in[22];
    const float* mi_b     = (const float*)d_in[23];
    const float* ssf_mi_s = (const float*)d_in[24];
    const float* ssf_mi_h = (const float*)d_in[25];
    const float* mo_w     = (const float*)d_in[26];
    const float* mo_b     = (const float*)d_in[27];
    const float* ssf_mo_s = (const float*)d_in[28];
    const float* ssf_mo_h = (const float*)d_in[29];
    const float* afln_g   = (const float*)d_in[30];
    const float* afln_b   = (const float*)d_in[31];
    const float* afd_w    = (const float*)d_in[32];
    const float* afd_b    = (const float*)d_in[33];
    const float* afu_w    = (const float*)d_in[34];
    const float* afu_b    = (const float*)d_in[35];
    const float* lnpost_g = (const float*)d_in[36];
    const float* lnpost_b = (const float*)d_in[37];

    // workspace layout (MPAD = 1664 rows)
    char* w = (char*)d_ws;
    float* qkv  = (float*)(w);                   // 15,335,424
    float* h    = (float*)(w + 15335424);        //  5,111,808
    bf16*  t    = (bf16*)(w + 20447232);         //  2,555,904
    bf16*  mm   = (bf16*)(w + 23003136);         // 10,223,616
    bf16*  ao   = (bf16*)(w + 33226752);         //  2,555,904
    bf16*  ad   = (bf16*)(w + 35782656);         //    212,992
    float* sq   = (float*)(w + 35995648);        //     53,248
    float* sv   = (float*)(w + 36048896);        //     53,248
    bf16*  wbuf = (bf16*)(w + 36102144);         // 14,352,384 (end 50,454,528)
    // aliases:
    float* aout  = qkv;                          // AF-up output; qkv dead after attn
    bf16*  Pm    = mm;                           // pre-loop only
    float* E     = (float*)(w + 25559040);       // pre-loop only (inside mm)
    float* h0    = qkv;                          // pre-loop only
    bf16*  wconv = wbuf;                         // pre-loop only

    const size_t WQ = 0, WO = 1769472, WMI = 2359296, WMO = 4718592, WAD = 7077888, WAU = 7127040;

    // ---- patch embed ----
    cvt8_k<<<288, 256, 0, stream>>>(conv_w, wconv);
    patch_k<<<4704, 256, 0, stream>>>(X, Pm);
    gemm128_k<0,false,0,false><<<dim3(6,13), 256, 0, stream>>>(Pm, wconv,
        nullptr, nullptr, nullptr, nullptr, nullptr, E, 768, 768);
    assemble_k<<<4729, 256, 0, stream>>>(E, cls, pos, h0);
    ln_k<false><<<394, 256, 0, stream>>>(h0, h, lnpre_g, lnpre_b);

    for (int i = 0; i < 12; ++i) {
        cvtlayer_k<<<3504, 256, 0, stream>>>(
            qkv_w + (size_t)i * 1769472u, out_w + (size_t)i * 589824u,
            mi_w  + (size_t)i * 2359296u, mo_w  + (size_t)i * 2359296u,
            afd_w + (size_t)i * 49152u,   afu_w + (size_t)i * 49152u, wbuf);
        // attention
        ln_k<true><<<394, 256, 0, stream>>>(h, t, ln1_g + i*768, ln1_b + i*768);
        gemm128_k<0,true,0,false><<<dim3(18,13), 256, 0, stream>>>(t, wbuf + WQ,
            qkv_b + i*2304, ssf_in_s + i*2304, ssf_in_h + i*2304, nullptr, nullptr, qkv, 2304, 768);
        lora_down2_k<<<dim3(394,2), 256, 0, stream>>>(t,
            lora_q_a + (size_t)i*6144, lora_v_a + (size_t)i*6144, sq, sv);
        lora_up2_k<<<dim3(4729,2), 256, 0, stream>>>(sq, sv,
            lora_q_b + (size_t)i*6144, lora_v_b + (size_t)i*6144, qkv);
        attn3_k<<<dim3(4,96), 256, 0, stream>>>(qkv, ao);
        gemm128_k<0,true,1,false><<<dim3(6,13), 256, 0, stream>>>(ao, wbuf + WO,
            out_b + i*768, ssf_o_s + i*768, ssf_o_h + i*768, h, nullptr, h, 768, 768);
        // AdaptFormer parallel branch
        ln_k<true><<<394, 256, 0, stream>>>(h, t, afln_g + i*768, afln_b + i*768);
        afdown_k<<<26, 256, 0, stream>>>(t, wbuf + WAD, afd_b + i*64, ad);
        gemm128_k<3,false,0,false><<<dim3(6,13), 256, 0, stream>>>(ad, wbuf + WAU,
            afu_b + i*768, nullptr, nullptr, nullptr, nullptr, aout, 768, 64);
        // MLP
        ln_k<true><<<394, 256, 0, stream>>>(h, t, ln2_g + i*768, ln2_b + i*768);
        gemm128_k<2,true,0,true><<<dim3(24,13), 256, 0, stream>>>(t, wbuf + WMI,
            mi_b + i*3072, ssf_mi_s + i*3072, ssf_mi_h + i*3072, nullptr, nullptr, mm, 3072, 768);
        gemm128_k<0,true,2,false><<<dim3(6,13), 256, 0, stream>>>(mm, wbuf + WMO,
            mo_b + i*768, ssf_mo_s + i*768, ssf_mo_h + i*768, h, aout, h, 768, 3072);
    }
    lnpost_k<<<2, 256, 0, stream>>>(h, (float*)d_out, lnpost_g, lnpost_b);
}

// Round 5
// 2157.936 us; speedup vs baseline: 3.3962x; 1.4463x over previous
//
#include <hip/hip_runtime.h>
#include <hip/hip_bf16.h>
#include <stdint.h>

typedef __hip_bfloat16 bf16;
typedef short v8s __attribute__((ext_vector_type(8)));
typedef float v4f __attribute__((ext_vector_type(4)));

#define D_ 768
#define S_ 197
#define MREAL 1576
#define MPAD 1664

__device__ __forceinline__ float b2f(bf16 x){ return __bfloat162float(x); }
__device__ __forceinline__ bf16 f2b(float x){ return __float2bfloat16(x); }
__device__ __forceinline__ unsigned short f2bits(float x){
    union { float f; unsigned u; } t; t.f = x;
    unsigned r = (t.u + 0x7fffu + ((t.u >> 16) & 1u)) >> 16;   // RNE
    return (unsigned short)r;
}
__device__ __forceinline__ v8s pack8(const float4 a, const float4 b){
    union { v8s v; unsigned short u[8]; } r;
    r.u[0]=f2bits(a.x); r.u[1]=f2bits(a.y); r.u[2]=f2bits(a.z); r.u[3]=f2bits(a.w);
    r.u[4]=f2bits(b.x); r.u[5]=f2bits(b.y); r.u[6]=f2bits(b.z); r.u[7]=f2bits(b.w);
    return r.v;
}
__device__ __forceinline__ float dot8(const float* __restrict__ b, const float* __restrict__ s){
    float4 b0 = *(const float4*)b, b1 = *(const float4*)(b + 4);
    return b0.x*s[0]+b0.y*s[1]+b0.z*s[2]+b0.w*s[3]+b1.x*s[4]+b1.y*s[5]+b1.z*s[6]+b1.w*s[7];
}

// async global->LDS, 16B per lane, wave-uniform LDS base + lane*16
__device__ __forceinline__ void gload16(const void* g, void* l) {
    __builtin_amdgcn_global_load_lds(
        (const __attribute__((address_space(1))) void*)(uintptr_t)g,
        (__attribute__((address_space(3))) void*)(uint32_t)(uintptr_t)l,
        16, 0, 0);
}

#define MFMA __builtin_amdgcn_mfma_f32_16x16x32_bf16

// ---------------- 128x64 MFMA GEMM, BK=64, 8 waves, xor-swizzled LDS ----------------
// A: [MPAD,K] bf16 row-major. W: [N,K] bf16 row-major. C = A@W^T.
// SPLIT: raw f32 partial to Cout + z*MPAD*N. ACT: 0 none,1 relu,2 qgelu,3 *0.1
template<int ACT, bool SSF, int NRES, bool OUTBF, bool SPLIT>
__global__ __launch_bounds__(512,2) void gemmA_k(
    const bf16* __restrict__ A, const bf16* __restrict__ W,
    const float* __restrict__ bias, const float* __restrict__ ssf_s, const float* __restrict__ ssf_h,
    const float* res1, const float* res2, void* Cout, int N, int K, int kc)
{
    __shared__ __align__(16) bf16 As[128*64];   // 16 KB
    __shared__ __align__(16) bf16 Bs[64*64];    //  8 KB
    const int tid = threadIdx.x, wid = tid >> 6, lane = tid & 63;
    const int lr = lane & 15, lq = lane >> 4;
    const int bm = blockIdx.y << 7, bn = blockIdx.x << 6;
    const int wm = (wid >> 1) << 5, wn = (wid & 1) << 5;
    const int kz0 = blockIdx.z * kc;

    // staging: lane l stages 16B group; row-in-8 = l>>3; xor-swizzle: global group = (l&7)^(l>>3)
    const int l8 = lane >> 3, g8 = ((lane & 7) ^ l8) << 3;
    const bf16* gA0 = A + (size_t)(bm + wid*16 + l8) * K + kz0 + g8;
    const bf16* gA1 = gA0 + (size_t)8 * K;
    const bf16* gB0 = W + (size_t)(bn + wid*8 + l8) * K + kz0 + g8;
    bf16* lA0 = As + wid*1024;
    bf16* lA1 = As + wid*1024 + 512;
    bf16* lB0 = Bs + wid*512;

    // loop-invariant LDS fragment addresses (swizzled group position)
    const int gl0 = (lq ^ (lr & 7)) << 3;
    const int gl1 = ((4 + lq) ^ (lr & 7)) << 3;
    const bf16* a0p = As + (wm + lr)*64;
    const bf16* a1p = As + (wm + 16 + lr)*64;
    const bf16* b0p = Bs + (wn + lr)*64;
    const bf16* b1p = Bs + (wn + 16 + lr)*64;

    v4f acc[2][2];
    #pragma unroll
    for (int a = 0; a < 2; ++a)
        #pragma unroll
        for (int b = 0; b < 2; ++b) acc[a][b] = (v4f){0.f,0.f,0.f,0.f};

    for (int k0 = 0; k0 < kc; k0 += 64) {
        gload16(gA0 + k0, lA0);
        gload16(gA1 + k0, lA1);
        gload16(gB0 + k0, lB0);
        __syncthreads();
        v8s a00 = *(const v8s*)(a0p + gl0), a01 = *(const v8s*)(a0p + gl1);
        v8s a10 = *(const v8s*)(a1p + gl0), a11 = *(const v8s*)(a1p + gl1);
        v8s b00 = *(const v8s*)(b0p + gl0), b01 = *(const v8s*)(b0p + gl1);
        v8s b10 = *(const v8s*)(b1p + gl0), b11 = *(const v8s*)(b1p + gl1);
        acc[0][0] = MFMA(a00, b00, acc[0][0], 0,0,0);
        acc[0][1] = MFMA(a00, b10, acc[0][1], 0,0,0);
        acc[1][0] = MFMA(a10, b00, acc[1][0], 0,0,0);
        acc[1][1] = MFMA(a10, b10, acc[1][1], 0,0,0);
        acc[0][0] = MFMA(a01, b01, acc[0][0], 0,0,0);
        acc[0][1] = MFMA(a01, b11, acc[0][1], 0,0,0);
        acc[1][0] = MFMA(a11, b01, acc[1][0], 0,0,0);
        acc[1][1] = MFMA(a11, b11, acc[1][1], 0,0,0);
        __syncthreads();
    }

    if (SPLIT) {
        float* P = (float*)Cout + (size_t)blockIdx.z * MPAD * N;
        #pragma unroll
        for (int mi = 0; mi < 2; ++mi)
            #pragma unroll
            for (int r = 0; r < 4; ++r) {
                int row = bm + wm + mi*16 + lq*4 + r;
                #pragma unroll
                for (int ni = 0; ni < 2; ++ni)
                    P[(size_t)row * N + bn + wn + ni*16 + lr] = acc[mi][ni][r];
            }
        return;
    }
    float bia[2], ss[2], sh[2];
    #pragma unroll
    for (int ni = 0; ni < 2; ++ni) {
        int col = bn + wn + ni*16 + lr;
        bia[ni] = bias ? bias[col] : 0.f;
        ss[ni] = SSF ? ssf_s[col] : 1.f;
        sh[ni] = SSF ? ssf_h[col] : 0.f;
    }
    #pragma unroll
    for (int mi = 0; mi < 2; ++mi)
        #pragma unroll
        for (int r = 0; r < 4; ++r) {
            int row = bm + wm + mi*16 + lq*4 + r;
            size_t rowoff = (size_t)row * N;
            #pragma unroll
            for (int ni = 0; ni < 2; ++ni) {
                int col = bn + wn + ni*16 + lr;
                float v = acc[mi][ni][r] + bia[ni];
                if (SSF) v = v * ss[ni] + sh[ni];
                if (ACT == 1) v = fmaxf(v, 0.f);
                if (ACT == 2) v = v / (1.f + __expf(-1.702f * v));
                if (ACT == 3) v = v * 0.1f;
                if (NRES >= 1) v += res1[rowoff + col];
                if (NRES >= 2) v += res2[rowoff + col];
                if (OUTBF) ((bf16*)Cout)[rowoff + col] = f2b(v);
                else       ((float*)Cout)[rowoff + col] = v;
            }
        }
}

// ---------------- split-K combine: out = ssf(P0+P1+bias) + res1 (+res2), N=768 ----------------
template<int NRES>
__global__ void combine_k(const float* __restrict__ P, const float* __restrict__ bias,
                          const float* __restrict__ ss, const float* __restrict__ sh,
                          const float* __restrict__ res1, const float* __restrict__ res2,
                          float* __restrict__ out)
{
    int idx = blockIdx.x * 256 + threadIdx.x;
    if (idx >= MREAL * 768) return;
    int col = idx % 768;
    float v = P[idx] + P[idx + MPAD*768] + bias[col];
    v = v * ss[col] + sh[col];
    v += res1[idx];
    if (NRES >= 2) v += res2[idx];
    out[idx] = v;
}

// ---------------- AF down: N=64, K=768, direct-load 64-tile GEMM, relu+bias -> bf16 ----------------
__global__ __launch_bounds__(256) void afdown_k(const bf16* __restrict__ A, const bf16* __restrict__ W,
                                                const float* __restrict__ bias, bf16* __restrict__ C)
{
    const int wid = threadIdx.x >> 6, lane = threadIdx.x & 63;
    const int lr = lane & 15, lq = lane >> 4;
    const int bm = blockIdx.x << 6;
    const int wm = (wid >> 1) << 5, wn = (wid & 1) << 5;

    v4f acc[2][2];
    #pragma unroll
    for (int a = 0; a < 2; ++a)
        #pragma unroll
        for (int b = 0; b < 2; ++b) acc[a][b] = (v4f){0.f,0.f,0.f,0.f};

    const v8s* A0 = (const v8s*)(A + (size_t)(bm + wm + lr) * 768 + lq * 8);
    const v8s* A1 = (const v8s*)(A + (size_t)(bm + wm + 16 + lr) * 768 + lq * 8);
    const v8s* B0 = (const v8s*)(W + (size_t)(wn + lr) * 768 + lq * 8);
    const v8s* B1 = (const v8s*)(W + (size_t)(wn + 16 + lr) * 768 + lq * 8);
    for (int t = 0; t < 24; ++t) {
        v8s a0 = A0[t << 2], a1 = A1[t << 2];
        v8s b0 = B0[t << 2], b1 = B1[t << 2];
        acc[0][0] = MFMA(a0, b0, acc[0][0], 0, 0, 0);
        acc[0][1] = MFMA(a0, b1, acc[0][1], 0, 0, 0);
        acc[1][0] = MFMA(a1, b0, acc[1][0], 0, 0, 0);
        acc[1][1] = MFMA(a1, b1, acc[1][1], 0, 0, 0);
    }
    #pragma unroll
    for (int im = 0; im < 2; ++im)
        #pragma unroll
        for (int r = 0; r < 4; ++r) {
            int row = bm + wm + im*16 + lq*4 + r;
            #pragma unroll
            for (int in = 0; in < 2; ++in) {
                int col = wn + in*16 + lr;
                float v = fmaxf(acc[im][in][r] + bias[col], 0.f);
                C[(size_t)row * 64 + col] = f2b(v);
            }
        }
}

// ---------------- LayerNorm: one wave per row; optional fused LoRA-down ----------------
template<bool OUTBF, bool LORA>
__global__ __launch_bounds__(256) void ln_k(const float* __restrict__ X, void* Y,
                                            const float* __restrict__ g, const float* __restrict__ b,
                                            const float* __restrict__ Aq, const float* __restrict__ Av,
                                            float* __restrict__ sq, float* __restrict__ sv)
{
    int wid = threadIdx.x >> 6, lane = threadIdx.x & 63;
    int row = blockIdx.x * 4 + wid;
    const float* x = X + (size_t)row * D_;
    float v[12], s = 0.f;
    #pragma unroll
    for (int i = 0; i < 12; ++i) { v[i] = x[lane + i * 64]; s += v[i]; }
    #pragma unroll
    for (int o = 32; o; o >>= 1) s += __shfl_xor(s, o, 64);
    float mean = s * (1.f / 768.f);
    float q = 0.f;
    #pragma unroll
    for (int i = 0; i < 12; ++i) { float d = v[i] - mean; q += d * d; }
    #pragma unroll
    for (int o = 32; o; o >>= 1) q += __shfl_xor(q, o, 64);
    float rs = rsqrtf(q * (1.f / 768.f) + 1e-5f);
    float aq[8], av[8];
    if (LORA) {
        #pragma unroll
        for (int r = 0; r < 8; ++r) { aq[r] = 0.f; av[r] = 0.f; }
    }
    #pragma unroll
    for (int i = 0; i < 12; ++i) {
        int d = lane + i * 64;
        float o = (v[i] - mean) * rs * g[d] + b[d];
        if (OUTBF) ((bf16*)Y)[(size_t)row * D_ + d] = f2b(o);
        else       ((float*)Y)[(size_t)row * D_ + d] = o;
        if (LORA) {
            #pragma unroll
            for (int r = 0; r < 8; ++r) {
                aq[r] += o * Aq[r * D_ + d];
                av[r] += o * Av[r * D_ + d];
            }
        }
    }
    if (LORA) {
        #pragma unroll
        for (int r = 0; r < 8; ++r) {
            #pragma unroll
            for (int off = 32; off; off >>= 1) {
                aq[r] += __shfl_xor(aq[r], off, 64);
                av[r] += __shfl_xor(av[r], off, 64);
            }
        }
        if (lane == 0) {
            #pragma unroll
            for (int r = 0; r < 8; ++r) { sq[row * 8 + r] = aq[r]; sv[row * 8 + r] = av[r]; }
        }
    }
}

__global__ __launch_bounds__(256) void lnpost_k(const float* __restrict__ X, float* out,
                                                const float* __restrict__ g, const float* __restrict__ b)
{
    int wid = threadIdx.x >> 6, lane = threadIdx.x & 63;
    int bi = blockIdx.x * 4 + wid;   // 0..7
    const float* x = X + (size_t)bi * S_ * D_;
    float v[12], s = 0.f;
    #pragma unroll
    for (int i = 0; i < 12; ++i) { v[i] = x[lane + i * 64]; s += v[i]; }
    #pragma unroll
    for (int o = 32; o; o >>= 1) s += __shfl_xor(s, o, 64);
    float mean = s * (1.f / 768.f);
    float q = 0.f;
    #pragma unroll
    for (int i = 0; i < 12; ++i) { float d = v[i] - mean; q += d * d; }
    #pragma unroll
    for (int o = 32; o; o >>= 1) q += __shfl_xor(q, o, 64);
    float rs = rsqrtf(q * (1.f / 768.f) + 1e-5f);
    #pragma unroll
    for (int i = 0; i < 12; ++i) {
        int d = lane + i * 64;
        out[bi * D_ + d] = (v[i] - mean) * rs * g[d] + b[d];
    }
}

// ---------------- MFMA flash attention with fused LoRA-up on Q and V ----------------
__global__ __launch_bounds__(256) void attn3_k(const float* __restrict__ qkv,
                                               const float* __restrict__ sq, const float* __restrict__ sv,
                                               const float* __restrict__ Bq, const float* __restrict__ Bv,
                                               bf16* __restrict__ o)
{
    __shared__ __align__(16) unsigned short smA[14336];
    __shared__ __align__(16) unsigned short smV[14336];
    const int tid = threadIdx.x, wid = tid >> 6, lane = tid & 63;
    const int quad = lane >> 4, l15 = lane & 15;
    const int qblk = blockIdx.x, bh = blockIdx.y;
    const int hh = bh % 12, bb = bh / 12;
    const size_t base = (size_t)(bb * S_) * 2304;

    // ---- stage K in B-fragment order
    for (int idx = tid; idx < 197 * 32; idx += 256) {
        int key = idx >> 5, d = (idx & 31) << 1;
        float2 f = *(const float2*)(qkv + base + (size_t)key * 2304 + 768 + hh * 64 + d);
        unsigned pr = (unsigned)f2bits(f.x) | ((unsigned)f2bits(f.y) << 16);
        int elem = ((key >> 4) << 10) + ((d >> 5) << 9) + (((d & 31) >> 3) << 7) + ((key & 15) << 3) + (d & 7);
        *(unsigned*)(smA + elem) = pr;
    }
    // ---- stage V (+ LoRA) in B-fragment order (keys 197..223 zero)
    for (int idx = tid; idx < 224 * 64; idx += 256) {
        int key = idx >> 6, d = idx & 63;
        unsigned short hv = 0;
        if (key < 197) {
            float v = qkv[base + (size_t)key * 2304 + 1536 + hh * 64 + d];
            v += dot8(Bv + (size_t)(hh * 64 + d) * 8, sv + (size_t)(bb * S_ + key) * 8);
            hv = f2bits(v);
        }
        int elem = (((key >> 5) << 2) + (d >> 4)) * 512 + (((key >> 3) & 3) * 16 + (d & 15)) * 8 + (key & 7);
        smV[elem] = hv;
    }
    __syncthreads();

    const int q0 = qblk * 64 + wid * 16;
    const bool active = (q0 < 208);
    v4f sc[13];
    float inv[4];
    if (active) {
        int qrow = q0 + l15; if (qrow > 196) qrow = 196;
        const float* qp = qkv + base + (size_t)qrow * 2304 + hh * 64 + quad * 8;
        float sql[8];
        const float* sqp = sq + (size_t)(bb * S_ + qrow) * 8;
        #pragma unroll
        for (int r = 0; r < 8; ++r) sql[r] = sqp[r];
        union { v8s v; unsigned short u[8]; } q0u, q1u;
        #pragma unroll
        for (int j = 0; j < 8; ++j) {
            int d0 = quad * 8 + j;
            q0u.u[j] = f2bits(qp[j]      + dot8(Bq + (size_t)(hh * 64 + d0) * 8, sql));
            q1u.u[j] = f2bits(qp[32 + j] + dot8(Bq + (size_t)(hh * 64 + d0 + 32) * 8, sql));
        }
        v8s qf0 = q0u.v, qf1 = q1u.v;
        #pragma unroll
        for (int kt = 0; kt < 13; ++kt) {
            sc[kt] = (v4f){0.f,0.f,0.f,0.f};
            sc[kt] = MFMA(qf0, *(const v8s*)&smA[kt*1024 + lane*8],       sc[kt], 0,0,0);
            sc[kt] = MFMA(qf1, *(const v8s*)&smA[kt*1024 + 512 + lane*8], sc[kt], 0,0,0);
        }
        float mx[4] = {-1e30f,-1e30f,-1e30f,-1e30f};
        #pragma unroll
        for (int kt = 0; kt < 13; ++kt)
            #pragma unroll
            for (int r = 0; r < 4; ++r) {
                float v = sc[kt][r] * 0.125f;
                if (kt == 12 && l15 >= 5) v = -1e30f;
                sc[kt][r] = v;
                mx[r] = fmaxf(mx[r], v);
            }
        #pragma unroll
        for (int r = 0; r < 4; ++r)
            #pragma unroll
            for (int off = 1; off < 16; off <<= 1) mx[r] = fmaxf(mx[r], __shfl_xor(mx[r], off, 64));
        float sum[4] = {0.f,0.f,0.f,0.f};
        #pragma unroll
        for (int kt = 0; kt < 13; ++kt)
            #pragma unroll
            for (int r = 0; r < 4; ++r) {
                float p = (kt == 12 && l15 >= 5) ? 0.f : __expf(sc[kt][r] - mx[r]);
                sc[kt][r] = p;
                sum[r] += p;
            }
        #pragma unroll
        for (int r = 0; r < 4; ++r) {
            #pragma unroll
            for (int off = 1; off < 16; off <<= 1) sum[r] += __shfl_xor(sum[r], off, 64);
            inv[r] = 1.f / sum[r];
        }
    }
    __syncthreads();
    if (active) {
        unsigned short* pf = smA + wid * 3584;
        *(unsigned long long*)(pf + 6*512 + 256 + lane*4) = 0ULL;
        #pragma unroll
        for (int kt = 0; kt < 13; ++kt) {
            int key = kt * 16 + l15;
            int ebase = ((key >> 5) << 9) + (((key >> 3) & 3) << 7) + (key & 7);
            #pragma unroll
            for (int r = 0; r < 4; ++r) pf[ebase + (quad * 4 + r) * 8] = f2bits(sc[kt][r]);
        }
        v4f oa[4];
        #pragma unroll
        for (int nt = 0; nt < 4; ++nt) oa[nt] = (v4f){0.f,0.f,0.f,0.f};
        #pragma unroll
        for (int kt2 = 0; kt2 < 7; ++kt2) {
            v8s pfr = *(const v8s*)(pf + kt2 * 512 + lane * 8);
            #pragma unroll
            for (int nt = 0; nt < 4; ++nt) {
                v8s vf = *(const v8s*)(smV + (kt2 * 4 + nt) * 512 + lane * 8);
                oa[nt] = MFMA(pfr, vf, oa[nt], 0, 0, 0);
            }
        }
        #pragma unroll
        for (int r = 0; r < 4; ++r) {
            int q = q0 + quad * 4 + r;
            if (q < 197) {
                bf16* op = o + (size_t)(bb * S_ + q) * 768 + hh * 64 + l15;
                #pragma unroll
                for (int nt = 0; nt < 4; ++nt) op[nt * 16] = f2b(oa[nt][r] * inv[r]);
            }
        }
    }
}

// ---------------- patch gather ----------------
__global__ void patch_k(const float* __restrict__ x, bf16* __restrict__ Pm)
{
    int idx = blockIdx.x * 256 + threadIdx.x;   // 1568*768 exact
    int col = idx % 768, row = idx / 768;
    int b = row / 196, p = row % 196;
    int py = p / 14, px = p % 14;
    int c = col >> 8, rem = col & 255, kh = rem >> 4, kw = rem & 15;
    Pm[idx] = f2b(x[(((size_t)(b * 3 + c) * 224 + py * 16 + kh) * 224) + px * 16 + kw]);
}

__global__ void assemble_k(const float* __restrict__ E, const float* __restrict__ cls,
                           const float* __restrict__ pos, float* __restrict__ h0)
{
    int idx = blockIdx.x * 256 + threadIdx.x;
    if (idx >= MREAL * D_) return;
    int d = idx % D_, row = idx / D_;
    int b = row / S_, s = row % S_;
    float v = (s == 0) ? cls[d] : E[(size_t)(b * 196 + s - 1) * D_ + d];
    h0[idx] = v + pos[s * D_ + d];
}

// ---------------- weight conversion f32 -> bf16 ----------------
__global__ void cvt8_k(const float* __restrict__ src, bf16* __restrict__ dst)
{
    size_t i8 = (size_t)(blockIdx.x * 256 + threadIdx.x) * 8;
    float4 a = *(const float4*)(src + i8);
    float4 b = *(const float4*)(src + i8 + 4);
    *(v8s*)(dst + i8) = pack8(a, b);
}

// layer weights: [qkv 1769472][out 589824][mi 2359296][mo 2359296][afd 49152][afu 49152]
__global__ void cvtlayer_k(const float* __restrict__ s0, const float* __restrict__ s1,
                           const float* __restrict__ s2, const float* __restrict__ s3,
                           const float* __restrict__ s4, const float* __restrict__ s5,
                           bf16* __restrict__ dst)
{
    size_t i8 = (size_t)(blockIdx.x * 256 + threadIdx.x) * 8;
    const float* src; size_t loc;
    if      (i8 < 1769472u) { src = s0; loc = i8; }
    else if (i8 < 2359296u) { src = s1; loc = i8 - 1769472u; }
    else if (i8 < 4718592u) { src = s2; loc = i8 - 2359296u; }
    else if (i8 < 7077888u) { src = s3; loc = i8 - 4718592u; }
    else if (i8 < 7127040u) { src = s4; loc = i8 - 7077888u; }
    else                    { src = s5; loc = i8 - 7127040u; }
    float4 a = *(const float4*)(src + loc);
    float4 b = *(const float4*)(src + loc + 4);
    *(v8s*)(dst + i8) = pack8(a, b);
}

extern "C" void kernel_launch(void* const* d_in, const int* in_sizes, int n_in,
                              void* d_out, int out_size, void* d_ws, size_t ws_size,
                              hipStream_t stream)
{
    (void)in_sizes; (void)n_in; (void)out_size; (void)ws_size;
    const float* X        = (const float*)d_in[0];
    const float* conv_w   = (const float*)d_in[1];
    const float* cls      = (const float*)d_in[2];
    const float* pos      = (const float*)d_in[3];
    const float* lnpre_g  = (const float*)d_in[4];
    const float* lnpre_b  = (const float*)d_in[5];
    const float* ln1_g    = (const float*)d_in[6];
    const float* ln1_b    = (const float*)d_in[7];
    const float* qkv_w    = (const float*)d_in[8];
    const float* qkv_b    = (const float*)d_in[9];
    const float* ssf_in_s = (const float*)d_in[10];
    const float* ssf_in_h = (const float*)d_in[11];
    const float* lora_q_a = (const float*)d_in[12];
    const float* lora_q_b = (const float*)d_in[13];
    const float* lora_v_a = (const float*)d_in[14];
    const float* lora_v_b = (const float*)d_in[15];
    const float* out_w    = (const float*)d_in[16];
    const float* out_b    = (const float*)d_in[17];
    const float* ssf_o_s  = (const float*)d_in[18];
    const float* ssf_o_h  = (const float*)d_in[19];
    const float* ln2_g    = (const float*)d_in[20];
    const float* ln2_b    = (const float*)d_in[21];
    const float* mi_w     = (const float*)d_in[22];
    const float* mi_b     = (const float*)d_in[23];
    const float* ssf_mi_s = (const float*)d_in[24];
    const float* ssf_mi_h = (const float*)d_in[25];
    const float* mo_w     = (const float*)d_in[26];
    const float* mo_b     = (const float*)d_in[27];
    const float* ssf_mo_s = (const float*)d_in[28];
    const float* ssf_mo_h = (const float*)d_in[29];
    const float* afln_g   = (const float*)d_in[30];
    const float* afln_b   = (const float*)d_in[31];
    const float* afd_w    = (const float*)d_in[32];
    const float* afd_b    = (const float*)d_in[33];
    const float* afu_w    = (const float*)d_in[34];
    const float* afu_b    = (const float*)d_in[35];
    const float* lnpost_g = (const float*)d_in[36];
    const float* lnpost_b = (const float*)d_in[37];

    // workspace layout (MPAD = 1664 rows)
    char* w = (char*)d_ws;
    float* qkv  = (float*)(w);                   // 15,335,424 (aout = first 5,111,808; P = next 10,223,616)
    float* P    = (float*)(w + 5111808);         // 2 x MPAD*768*4 split-K partials (inside qkv tail)
    float* h    = (float*)(w + 15335424);        //  5,111,808
    bf16*  t    = (bf16*)(w + 20447232);         //  2,555,904
    bf16*  mm   = (bf16*)(w + 23003136);         // 10,223,616
    bf16*  ao   = (bf16*)(w + 33226752);         //  2,555,904
    bf16*  ad   = (bf16*)(w + 35782656);         //    212,992
    float* sq   = (float*)(w + 35995648);        //     53,248
    float* sv   = (float*)(w + 36048896);        //     53,248
    bf16*  wbuf = (bf16*)(w + 36102144);         // 14,352,384 (end 50,454,528)
    float* aout  = qkv;                          // AF-up output
    bf16*  Pm    = mm;                           // pre-loop only
    float* E     = (float*)(w + 25559040);       // pre-loop only (inside mm)
    float* h0    = qkv;                          // pre-loop only
    bf16*  wconv = wbuf;                         // pre-loop only

    const size_t WQ = 0, WO = 1769472, WMI = 2359296, WMO = 4718592, WAD = 7077888, WAU = 7127040;

    // ---- patch embed ----
    cvt8_k<<<288, 256, 0, stream>>>(conv_w, wconv);
    patch_k<<<4704, 256, 0, stream>>>(X, Pm);
    gemmA_k<0,false,0,false,false><<<dim3(12,13), 512, 0, stream>>>(Pm, wconv,
        nullptr, nullptr, nullptr, nullptr, nullptr, E, 768, 768, 768);
    assemble_k<<<4729, 256, 0, stream>>>(E, cls, pos, h0);
    ln_k<false,false><<<394, 256, 0, stream>>>(h0, h, lnpre_g, lnpre_b, nullptr, nullptr, nullptr, nullptr);

    for (int i = 0; i < 12; ++i) {
        cvtlayer_k<<<3504, 256, 0, stream>>>(
            qkv_w + (size_t)i * 1769472u, out_w + (size_t)i * 589824u,
            mi_w  + (size_t)i * 2359296u, mo_w  + (size_t)i * 2359296u,
            afd_w + (size_t)i * 49152u,   afu_w + (size_t)i * 49152u, wbuf);
        // attention (LN1 + fused LoRA-down)
        ln_k<true,true><<<394, 256, 0, stream>>>(h, t, ln1_g + i*768, ln1_b + i*768,
            lora_q_a + (size_t)i*6144, lora_v_a + (size_t)i*6144, sq, sv);
        gemmA_k<0,true,0,false,false><<<dim3(36,13), 512, 0, stream>>>(t, wbuf + WQ,
            qkv_b + i*2304, ssf_in_s + i*2304, ssf_in_h + i*2304, nullptr, nullptr, qkv, 2304, 768, 768);
        attn3_k<<<dim3(4,96), 256, 0, stream>>>(qkv, sq, sv,
            lora_q_b + (size_t)i*6144, lora_v_b + (size_t)i*6144, ao);
        gemmA_k<0,false,0,false,true><<<dim3(12,13,2), 512, 0, stream>>>(ao, wbuf + WO,
            nullptr, nullptr, nullptr, nullptr, nullptr, P, 768, 768, 384);
        combine_k<1><<<4729, 256, 0, stream>>>(P, out_b + i*768,
            ssf_o_s + i*768, ssf_o_h + i*768, h, nullptr, h);
        // AdaptFormer parallel branch
        ln_k<true,false><<<394, 256, 0, stream>>>(h, t, afln_g + i*768, afln_b + i*768,
            nullptr, nullptr, nullptr, nullptr);
        afdown_k<<<26, 256, 0, stream>>>(t, wbuf + WAD, afd_b + i*64, ad);
        gemmA_k<3,false,0,false,false><<<dim3(12,13), 512, 0, stream>>>(ad, wbuf + WAU,
            afu_b + i*768, nullptr, nullptr, nullptr, nullptr, aout, 768, 64, 64);
        // MLP
        ln_k<true,false><<<394, 256, 0, stream>>>(h, t, ln2_g + i*768, ln2_b + i*768,
            nullptr, nullptr, nullptr, nullptr);
        gemmA_k<2,true,0,true,false><<<dim3(48,13), 512, 0, stream>>>(t, wbuf + WMI,
            mi_b + i*3072, ssf_mi_s + i*3072, ssf_mi_h + i*3072, nullptr, nullptr, mm, 3072, 768, 768);
        gemmA_k<0,false,0,false,true><<<dim3(12,13,2), 512, 0, stream>>>(mm, wbuf + WMO,
            nullptr, nullptr, nullptr, nullptr, nullptr, P, 768, 3072, 1536);
        combine_k<2><<<4729, 256, 0, stream>>>(P, mo_b + i*768,
            ssf_mo_s + i*768, ssf_mo_h + i*768, h, aout, h);
    }
    lnpost_k<<<2, 256, 0, stream>>>(h, (float*)d_out, lnpost_g, lnpost_b);
}